// Round 10
// baseline (131.594 us; speedup 1.0000x reference)
//
#include <hip/hip_runtime.h>
#include <cstdint>
#include <cstddef>

typedef unsigned short u16;
typedef uint32_t u32;
typedef __bf16 bf16x8 __attribute__((ext_vector_type(8)));
typedef float f32x4 __attribute__((ext_vector_type(4)));
typedef float f32x16 __attribute__((ext_vector_type(16)));

typedef __attribute__((address_space(1))) void gvoid;
typedef __attribute__((address_space(3))) void lvoid;

__device__ __forceinline__ void g2l16(const void* g, void* l) {
    __builtin_amdgcn_global_load_lds((gvoid*)g, (lvoid*)l, 16, 0, 0);
}

__device__ __forceinline__ u16 f2bf(float f) {
    union { float f; uint32_t u; } v;
    v.f = f;
    uint32_t r = (v.u + 0x7FFFu + ((v.u >> 16) & 1u)) >> 16;
    return (u16)r;
}

// ================= compressed-class problem tables (per batch: 24 problems) ==============
__device__ const int T_h[24]  = {0, 1,1,1, 2,2,2,2,2,2,2, 3,3,3,3,3,3,3,3,3,3,3,3,3};
__device__ const int T_g[24]  = {0, 0,1,2, 0,1,2,3,4,5,6, 0,1,2,3,4,5,6,7,8,9,10,11,12};
__device__ const int T_qt[24] = {0, 64,86,108, 130,140,150,160,170,180,190,
                                 200,205,210,215,220,225,230,235,240,245,250,255,260};
__device__ const int T_LQ[24] = {2048, 683,683,682, 293,293,293,293,292,292,292,
                                 158,158,158,158,158,158,158,157,157,157,157,157,157};
__device__ const int T_ktB[24]= {0, 64,86,108, 140,150,160,170,180,190,130,
                                 245,250,255,260,200,205,210,215,220,225,230,235,240};
__device__ const int T_LkB[24]= {2048, 683,683,682, 293,293,293,292,292,292,293,
                                 157,157,157,157,158,158,158,158,158,158,158,157,157};
__device__ const int T_cB[24] = {1, -341,-341,-341, -146,-146,-146,-146,-146,-146,-145,
                                 -79,-79,-79,-79,-78,-78,-78,-78,-78,-78,-78,-78,-78};
__device__ const int T_ktA[24]= {0, 108,64,86, 180,190,130,140,150,160,170,
                                 215,220,225,230,235,240,245,250,255,260,200,205,210};
__device__ const int T_LkA[24]= {0, 682,683,683, 292,292,293,293,293,293,292,
                                 158,158,158,158,157,157,157,157,157,157,158,158,158};
__device__ const int T_cA[24] = {0, -342,-341,-341, -147,-147,-146,-146,-146,-146,-146,
                                 -79,-79,-79,-79,-79,-79,-79,-79,-79,-79,-78,-78,-78};
__device__ const int T_dA[24] = {0, 0,1,1, 0,0,1,1,1,1,1, 0,0,0,0,0,0,0,0,0,0,1,1,1};
__device__ const int T_nc[24] = {16, 6,6,6, 3,3,3,3,3,3,3, 2,2,2,2,2,2,2,2,2,2,2,2,2};

__device__ __forceinline__ void col_geom(int p, int c, int& ntB, int& tA0, int& nt) {
    const int LQ = T_LQ[p];
    const int Mc = c << 7;
    int mmax = Mc + 128; if (mmax > LQ) mmax = LQ; mmax -= 1;
    int jB = mmax + T_cB[p];
    if (jB < 0) jB = 0;
    if (jB > T_LkB[p]) jB = T_LkB[p];
    ntB = (jB + 31) >> 5;
    int jlo = Mc + T_cA[p]; if (jlo < 0) jlo = 0;
    int jhi = mmax + T_dA[p];
    if (jhi > T_LkA[p]) jhi = T_LkA[p];
    tA0 = jlo >> 5;
    int ntA = 0;
    if (jhi > jlo) ntA = ((jhi + 31) >> 5) - tA0;
    nt = ntB + ntA;
}

__device__ __forceinline__ u16* partO_addr(u16* lo, u16* hi, int slot) {
    return (slot < 128) ? (lo + (size_t)slot * 32768) : (hi + (size_t)(slot - 128) * 32768);
}
__device__ __forceinline__ const u16* partO_addr_c(const u16* lo, const u16* hi, int slot) {
    return (slot < 128) ? (lo + (size_t)slot * 32768) : (hi + (size_t)(slot - 128) * 32768);
}

// ---------------- fp32 -> bf16 conversion of x, Wqk, Wv, Wo into ws ----------------
__global__ __launch_bounds__(256)
void cvt_kernel(const float* __restrict__ x, const float* __restrict__ wqk,
                const float* __restrict__ wv, const float* __restrict__ wo,
                u16* __restrict__ out) {
    int i = (blockIdx.x * 256 + threadIdx.x) * 4;
    const float* src;
    int off;
    if (i < 4194304)      { src = x;   off = 0; }
    else if (i < 5242880) { src = wqk; off = 4194304; }
    else if (i < 6291456) { src = wv;  off = 5242880; }
    else                  { src = wo;  off = 6291456; }
    float4 v = *(const float4*)(src + (i - off));
    ushort4 o;
    o.x = f2bf(v.x); o.y = f2bf(v.y); o.z = f2bf(v.z); o.w = f2bf(v.w);
    *(ushort4*)(out + i) = o;
}

// ---------------- fused QK+V projection GEMM with class-pack epilogue ----------------
// BM=128 BN=64 BK=32, dbuf, 4 waves, grid 512. Epilogue bounces each 128x64 output tile
// through LDS (row-XOR swizzle) and writes kpack/vpack class-tile layouts directly.
__global__ __launch_bounds__(256, 3)
void gemm_qkv(const u16* __restrict__ A, const u16* __restrict__ Bq, const u16* __restrict__ Bv,
              const float* __restrict__ bq, const float* __restrict__ bv,
              u16* __restrict__ kpack, u16* __restrict__ vpack) {
    __shared__ __align__(16) u16 As[2][4096], Bqs[2][2048], Bvs[2][2048];
    const int bid = blockIdx.x;
    const int m0 = (bid >> 4) * 128;
    const int n0 = (bid & 15) * 64;
    const int t = threadIdx.x;
    const int lane = t & 63;
    const int wid = t >> 6;
    const int wr = wid >> 1, wc = wid & 1;
    const int l15 = lane & 15, l4 = lane >> 4;

    f32x4 aq[4][2] = {}, av[4][2] = {};

    auto stage = [&](int buf, int kt) {
        const int kbase = kt * 32;
#pragma unroll
        for (int c2 = 0; c2 < 2; ++c2) {
            const int pp = c2 * 4096 + t * 16;
            g2l16(A + (size_t)(m0 + (pp >> 6)) * 1024 + kbase + ((pp & 63) >> 1), (char*)As[buf] + pp);
        }
        const int pb = t * 16;
        const int rb = pb >> 6, kb = (pb & 63) >> 1;
        g2l16(Bq + (size_t)(n0 + rb) * 1024 + kbase + kb, (char*)Bqs[buf] + pb);
        g2l16(Bv + (size_t)(n0 + rb) * 1024 + kbase + kb, (char*)Bvs[buf] + pb);
    };

    stage(0, 0);
    asm volatile("s_waitcnt vmcnt(0)" ::: "memory");
    __syncthreads();

    int cur = 0;
    for (int kt = 0; kt < 32; ++kt) {
        if (kt + 1 < 32) stage(cur ^ 1, kt + 1);
        bf16x8 af[4], bfq[2], bfv[2];
#pragma unroll
        for (int mi = 0; mi < 4; ++mi)
            af[mi] = *(const bf16x8*)((const char*)As[cur] + (wr * 64 + mi * 16 + l15) * 64 + l4 * 16);
#pragma unroll
        for (int ni = 0; ni < 2; ++ni) {
            bfq[ni] = *(const bf16x8*)((const char*)Bqs[cur] + (wc * 32 + ni * 16 + l15) * 64 + l4 * 16);
            bfv[ni] = *(const bf16x8*)((const char*)Bvs[cur] + (wc * 32 + ni * 16 + l15) * 64 + l4 * 16);
        }
        __builtin_amdgcn_s_setprio(1);
#pragma unroll
        for (int mi = 0; mi < 4; ++mi)
#pragma unroll
            for (int ni = 0; ni < 2; ++ni) {
                aq[mi][ni] = __builtin_amdgcn_mfma_f32_16x16x32_bf16(af[mi], bfq[ni], aq[mi][ni], 0, 0, 0);
                av[mi][ni] = __builtin_amdgcn_mfma_f32_16x16x32_bf16(af[mi], bfv[ni], av[mi][ni], 0, 0, 0);
            }
        __builtin_amdgcn_s_setprio(0);
        asm volatile("s_waitcnt vmcnt(0)" ::: "memory");
        __syncthreads();
        cur ^= 1;
    }

    // ---------------- pack epilogue ----------------
    const int tm0 = m0 & 2047;
    const int b_  = m0 >> 11;
    const int hh  = n0 >> 8;
    const int dd0 = n0 & 255;
    const int sS  = (hh == 0) ? 1 : (hh == 1) ? 3 : (hh == 2) ? 7 : 13;
    const int cb0 = (hh == 0) ? 0 : (hh == 1) ? 64 : (hh == 2) ? 130 : 200;
    const int cbs = (hh == 0) ? 1 : (hh == 1) ? 22 : (hh == 2) ? 10 : 5;
    const size_t PB = (size_t)b_ * 265 * 8192;
    u16* lds = &As[0][0];                 // 16KB bounce buffer (staging dead after last barrier)
    const int mbase = m0 + wr * 64 + l4 * 4;
    const int nbase = n0 + wc * 32 + l15;
    const bool padfill = (tm0 == 1920);   // last m-panel zero-fills V pad slots

    // ---- Q/K pack ----
#pragma unroll
    for (int ni = 0; ni < 2; ++ni) {
        const int n = nbase + ni * 16;
        const int dloc2 = (n - n0) * 2;
        const float bq_ = bq[n];
#pragma unroll
        for (int mi = 0; mi < 4; ++mi)
#pragma unroll
            for (int r = 0; r < 4; ++r) {
                const int row = mbase + mi * 16 + r - m0;
                *(u16*)((char*)lds + row * 128 + (dloc2 ^ ((row & 7) << 4))) = f2bf(aq[mi][ni][r] + bq_);
            }
    }
    __syncthreads();
    {
        const int jK = t & 31;
        const int dof = (t >> 5) * 16;                       // byte offset of this 8-d chunk
        const int dK = dd0 + (t >> 5) * 8;
        const int destoff = (dK >> 4) * 512 + (((t >> 5) & 1) * 32 + jK) * 8;
        for (int cls = 0; cls < sS; ++cls) {
            const int jf = (tm0 - cls + sS - 1) / sS;
            const int jl = (tm0 + 127 - cls) / sS;
            const int baseT = cb0 + cbs * cls;
            for (int jt = jf >> 5; jt <= (jl >> 5); ++jt) {
                const int j = (jt << 5) + jK;
                if (j >= jf && j <= jl) {
                    const int row = cls + j * sS - tm0;
                    const bf16x8 v = *(const bf16x8*)((char*)lds + row * 128 + (dof ^ ((row & 7) << 4)));
                    *(bf16x8*)(kpack + PB + (size_t)(baseT + jt) * 8192 + destoff) = v;
                }
            }
        }
    }
    __syncthreads();

    // ---- V pack ----
#pragma unroll
    for (int ni = 0; ni < 2; ++ni) {
        const int n = nbase + ni * 16;
        const int dloc2 = (n - n0) * 2;
        const float bv_ = bv[n];
#pragma unroll
        for (int mi = 0; mi < 4; ++mi)
#pragma unroll
            for (int r = 0; r < 4; ++r) {
                const int row = mbase + mi * 16 + r - m0;
                *(u16*)((char*)lds + row * 128 + (dloc2 ^ ((row & 7) << 4))) = f2bf(av[mi][ni][r] + bv_);
            }
    }
    __syncthreads();
    {
        const int dV = dd0 + (t & 63);
        const int jg = t >> 6;
        const int dloc2 = (t & 63) * 2;
        const int destoff = ((jg >> 1) * 8 + (dV >> 5)) * 512 + ((jg & 1) * 32 + (dV & 31)) * 8;
        auto ldv = [&](int row) -> u16 {
            return *(const u16*)((char*)lds + row * 128 + (dloc2 ^ ((row & 7) << 4)));
        };
        for (int cls = 0; cls < sS; ++cls) {
            const int jf = (tm0 - cls + sS - 1) / sS;
            const int jl = (tm0 + 127 - cls) / sS;
            const int baseT = cb0 + cbs * cls;
            for (int jt = jf >> 5; jt <= (jl >> 5); ++jt) {
                const int jb = (jt << 5) + jg * 8;
                int e0 = jf - jb; if (e0 < 0) e0 = 0;
                int ev = jl - jb; if (ev > 7) ev = 7;        // last valid e
                int e1w = ev;
                if (padfill && jt == (jl >> 5)) e1w = 7;     // zero-fill class-tail pads
                if (e0 > e1w) continue;
                const int rowb = cls + jb * sS - tm0;
                u16* dst = vpack + PB + (size_t)(baseT + jt) * 8192 + destoff;
                if (e0 == 0 && e1w == 7) {
                    const u16 a0 = (0 <= ev) ? ldv(rowb)          : (u16)0;
                    const u16 a1 = (1 <= ev) ? ldv(rowb + sS)     : (u16)0;
                    const u16 a2 = (2 <= ev) ? ldv(rowb + 2 * sS) : (u16)0;
                    const u16 a3 = (3 <= ev) ? ldv(rowb + 3 * sS) : (u16)0;
                    const u16 a4 = (4 <= ev) ? ldv(rowb + 4 * sS) : (u16)0;
                    const u16 a5 = (5 <= ev) ? ldv(rowb + 5 * sS) : (u16)0;
                    const u16 a6 = (6 <= ev) ? ldv(rowb + 6 * sS) : (u16)0;
                    const u16 a7 = (7 <= ev) ? ldv(rowb + 7 * sS) : (u16)0;
                    uint4 pk;
                    pk.x = (u32)a0 | ((u32)a1 << 16);
                    pk.y = (u32)a2 | ((u32)a3 << 16);
                    pk.z = (u32)a4 | ((u32)a5 << 16);
                    pk.w = (u32)a6 | ((u32)a7 << 16);
                    *(uint4*)dst = pk;
                } else {
#pragma unroll
                    for (int e = 0; e < 8; ++e) {
                        if (e >= e0 && e <= e1w)
                            dst[e] = (e <= ev) ? ldv(rowb + e * sS) : (u16)0;
                    }
                }
            }
        }
    }
}

// ---------------- compressed flash attention: XCD-pinned, LDS double-buffered ----------
__global__ __launch_bounds__(256, 2)
void attn_kernel(const u16* __restrict__ kpack, const u16* __restrict__ vpack,
                 u16* __restrict__ attnb, u16* __restrict__ partLo, u16* __restrict__ partHi,
                 float* __restrict__ mlbuf) {
    __shared__ __align__(16) unsigned char sm[65536];
    static constexpr int CGc[24] = {0,16,22,28,34,37,40,43,46,49,52,55,
                                    57,59,61,63,65,67,69,71,73,75,77,79};
    static constexpr int EXc[24] = {0,56,64,72,80,82,84,86,88,90,92,94,
                                    94,94,94,94,94,94,94,94,94,94,94,94};
    static constexpr int Tpc[24] = {72,14,14,14,5,5,5,5,5,5,5,2,2,2,2,2,2,2,2,2,2,2,2,2};

    const int bid = blockIdx.x;
    const int xcd = bid & 7, slot = bid >> 3;
    const int b = xcd & 1, quad = xcd >> 1;
    int hsel, hcb;
    if (quad <= 1) {
        if (slot < 36)      { hsel = 0; hcb = quad * 36 + slot; }
        else if (slot < 49) { hsel = 3; hcb = quad * 13 + (slot - 36); }
        else return;
    } else if (quad == 2) {
        if (slot >= 42) return;
        hsel = 1; hcb = slot;
    } else {
        if (slot >= 35) return;
        hsel = 2; hcb = slot;
    }
    int p = (hsel == 0) ? 0 : (hsel == 1) ? 1 : (hsel == 2) ? 4 : 11;
    int rb = hcb;
    while (rb >= Tpc[p]) { rb -= Tpc[p]; ++p; }
    int colg = CGc[p], exb = EXc[p];

    const int LQ = T_LQ[p];
    const int cB = T_cB[p], cA = T_cA[p], dA = T_dA[p];
    const int LKB = T_LkB[p], LKA = T_LkA[p];
    const int ktB = T_ktB[p], ktA = T_ktA[p];
    const int h = T_h[p], g = T_g[p], nc = T_nc[p], qt0 = T_qt[p];
    const int s = (h == 0) ? 1 : (h == 1) ? 3 : (h == 2) ? 7 : 13;

    int col = 0, chunk = 0, ntB = 0, tA0 = 0, nt = 0;
    for (int c = nc - 1; c >= 0; --c) {
        const int Mc = c << 7;
        int mmax = Mc + 128; if (mmax > LQ) mmax = LQ; mmax -= 1;
        int jB = mmax + cB; if (jB < 0) jB = 0; if (jB > LKB) jB = LKB;
        const int nb = (jB + 31) >> 5;
        int jlo = Mc + cA; if (jlo < 0) jlo = 0;
        int jhi = mmax + dA; if (jhi > LKA) jhi = LKA;
        const int ta = jlo >> 5;
        const int na = (jhi > jlo) ? (((jhi + 31) >> 5) - ta) : 0;
        const int n = nb + na;
        const int nch2 = (n + 7) >> 3;
        if (rb < nch2) { col = c; chunk = rb; ntB = nb; tA0 = ta; nt = n; break; }
        rb -= nch2; ++colg; exb += nch2 - 1;
    }
    const int nch = (nt + 7) >> 3;
    const int PBi = b * 265;

    const int t = threadIdx.x;
    const int w = t >> 6;
    const int l = t & 63;
    const int l31 = l & 31, h5 = l >> 5;
    const int m = (col << 7) + (w << 5) + l31;     // compressed query index
    const float c2 = 0.09016844f;                  // (1/16) * log2(e)
    const int lane16 = l * 16;                     // byte offset in packed tile

    // Q fragments from kpack class-g list tile (coalesced)
    bf16x8 qf[16];
    {
        const u16* qb = kpack + (size_t)(PBi + qt0 + col * 4 + w) * 8192 + l * 8;
#pragma unroll
        for (int dc = 0; dc < 16; ++dc)
            qf[dc] = *(const bf16x8*)(qb + dc * 512);
    }

    auto tileof = [&](int tv) -> int {
        return (tv < ntB) ? (ktB + tv) : (ktA + tA0 + (tv - ntB));
    };
    auto stage = [&](int tv, int buf) {
        const size_t tb = (size_t)(PBi + tileof(tv)) * 8192;
        unsigned char* Kd = sm + buf * 32768;
        unsigned char* Vd = Kd + 16384;
#pragma unroll
        for (int i2 = 0; i2 < 4; ++i2) {
            const int off = i2 * 4096 + t * 16;
            g2l16(kpack + tb + (off >> 1), Kd + off);
            g2l16(vpack + tb + (off >> 1), Vd + off);
        }
    };

    const int tt0 = chunk * 8;
    int tt1 = tt0 + 8; if (tt1 > nt) tt1 = nt;

    f32x16 o[8] = {};
    float mrun = -3.0e38f, lrun = 0.0f;

    stage(tt0, 0);
    asm volatile("s_waitcnt vmcnt(0)" ::: "memory");
    __syncthreads();

    int buf = 0;
    for (int tv = tt0; tv < tt1; ++tv) {
        if (tv + 1 < tt1) stage(tv + 1, buf ^ 1);

        int j0, lo, hi;
        if (tv < ntB) { j0 = tv << 5; lo = -100000; hi = cB; }
        else { const int ta = tA0 + tv - ntB; j0 = ta << 5; lo = cA; hi = dA; }

        const unsigned char* Kb = sm + buf * 32768;
        const unsigned char* Vb = Kb + 16384;

        // S^T = K * Q^T
        f32x16 sacc = {};
        __builtin_amdgcn_s_setprio(1);
#pragma unroll
        for (int dc = 0; dc < 16; ++dc) {
            const bf16x8 kf = *(const bf16x8*)(Kb + dc * 1024 + lane16);
            sacc = __builtin_amdgcn_mfma_f32_32x32x16_bf16(kf, qf[dc], sacc, 0, 0, 0);
        }
        __builtin_amdgcn_s_setprio(0);

        // mask + online softmax, in place (lane-local; e = j - m)
        const int ebase = j0 - m;
        float tmax = -3.0e38f;
#pragma unroll
        for (int r = 0; r < 16; ++r) {
            const int km = (r & 3) + 8 * (r >> 2) + 4 * h5;
            const int e = ebase + km;
            const bool ok = (e >= lo) && (e < hi);
            sacc[r] = ok ? sacc[r] : -3.0e38f;
            tmax = fmaxf(tmax, sacc[r]);
        }
        tmax = fmaxf(tmax, __shfl_xor(tmax, 32, 64));
        if (!__all(tmax <= mrun + 8.0f)) {     // defer-max
            const float mnew = fmaxf(mrun, tmax);
            const float fsc = __builtin_amdgcn_exp2f((mrun - mnew) * c2);
            lrun *= fsc;
#pragma unroll
            for (int ch = 0; ch < 8; ++ch)
#pragma unroll
                for (int r = 0; r < 16; ++r)
                    o[ch][r] *= fsc;
            mrun = mnew;
        }
        float psum = 0.0f;
#pragma unroll
        for (int r = 0; r < 16; ++r) {
            const float pv = (sacc[r] > -1.0e37f) ? __builtin_amdgcn_exp2f((sacc[r] - mrun) * c2) : 0.0f;
            sacc[r] = pv;
            psum += pv;
        }
        lrun += psum;

        // P -> bf16 fragments: cvt_pk + permlane32_swap
        uint32_t w0, w1, w2, w3, w4, w5, w6, w7;
        asm("v_cvt_pk_bf16_f32 %0,%1,%2" : "=v"(w0) : "v"(sacc[0]),  "v"(sacc[1]));
        asm("v_cvt_pk_bf16_f32 %0,%1,%2" : "=v"(w1) : "v"(sacc[2]),  "v"(sacc[3]));
        asm("v_cvt_pk_bf16_f32 %0,%1,%2" : "=v"(w2) : "v"(sacc[4]),  "v"(sacc[5]));
        asm("v_cvt_pk_bf16_f32 %0,%1,%2" : "=v"(w3) : "v"(sacc[6]),  "v"(sacc[7]));
        asm("v_cvt_pk_bf16_f32 %0,%1,%2" : "=v"(w4) : "v"(sacc[8]),  "v"(sacc[9]));
        asm("v_cvt_pk_bf16_f32 %0,%1,%2" : "=v"(w5) : "v"(sacc[10]), "v"(sacc[11]));
        asm("v_cvt_pk_bf16_f32 %0,%1,%2" : "=v"(w6) : "v"(sacc[12]), "v"(sacc[13]));
        asm("v_cvt_pk_bf16_f32 %0,%1,%2" : "=v"(w7) : "v"(sacc[14]), "v"(sacc[15]));
        asm("v_permlane32_swap_b32 %0, %1" : "+v"(w0), "+v"(w2));
        asm("v_permlane32_swap_b32 %0, %1" : "+v"(w1), "+v"(w3));
        asm("v_permlane32_swap_b32 %0, %1" : "+v"(w4), "+v"(w6));
        asm("v_permlane32_swap_b32 %0, %1" : "+v"(w5), "+v"(w7));
        union { uint32_t u[4]; bf16x8 v; } p0u, p1u;
        p0u.u[0] = w0; p0u.u[1] = w1; p0u.u[2] = w2; p0u.u[3] = w3;
        p1u.u[0] = w4; p1u.u[1] = w5; p1u.u[2] = w6; p1u.u[3] = w7;

        // O^T += V^T * P^T
        __builtin_amdgcn_s_setprio(1);
#pragma unroll
        for (int kk = 0; kk < 2; ++kk) {
            const bf16x8 pf = kk ? p1u.v : p0u.v;
#pragma unroll
            for (int ch = 0; ch < 8; ++ch) {
                const bf16x8 vf = *(const bf16x8*)(Vb + (kk * 8 + ch) * 1024 + lane16);
                o[ch] = __builtin_amdgcn_mfma_f32_32x32x16_bf16(vf, pf, o[ch], 0, 0, 0);
            }
        }
        __builtin_amdgcn_s_setprio(0);

        asm volatile("s_waitcnt vmcnt(0)" ::: "memory");
        __syncthreads();
        buf ^= 1;
    }

    lrun += __shfl_xor(lrun, 32, 64);

    float scale = 1.0f;
    u16* ab;
    const int qm = (w << 5) + l31;
    if (nch == 1) {
        scale = (lrun > 0.0f) ? 1.0f / lrun : 0.0f;
        ab = attnb + ((size_t)(b * 2048 + g + m * s)) * 1024 + h * 256;
    } else {
        if (h5 == 0 && m < LQ) {
            const int colid = b * 81 + colg;
            mlbuf[(size_t)((colid * 8 + chunk) * 256) + qm * 2]     = mrun;
            mlbuf[(size_t)((colid * 8 + chunk) * 256) + qm * 2 + 1] = lrun;
        }
        if (chunk == 0)
            ab = attnb + ((size_t)(b * 2048 + g + m * s)) * 1024 + h * 256;
        else
            ab = partO_addr(partLo, partHi, b * 94 + exb + chunk - 1) + (size_t)qm * 256;
    }

    if (m < LQ) {
#pragma unroll
        for (int ch = 0; ch < 8; ++ch) {
#pragma unroll
            for (int g2 = 0; g2 < 4; ++g2) {
                ushort4 wv4;
                wv4.x = f2bf(o[ch][g2 * 4 + 0] * scale);
                wv4.y = f2bf(o[ch][g2 * 4 + 1] * scale);
                wv4.z = f2bf(o[ch][g2 * 4 + 2] * scale);
                wv4.w = f2bf(o[ch][g2 * 4 + 3] * scale);
                *(ushort4*)(ab + ch * 32 + 8 * g2 + 4 * h5) = wv4;
            }
        }
    }
}

// ---------------- combine chunked columns ----------------
__global__ __launch_bounds__(256)
void combine_kernel(const u16* __restrict__ partLo, const u16* __restrict__ partHi,
                    const float* __restrict__ mlbuf, u16* __restrict__ attnb) {
    static constexpr int MCc[24] = {0,14,18,22,26,28,30,32,34,36,38,40,
                                    40,40,40,40,40,40,40,40,40,40,40,40};
    static constexpr int CGc[24] = {0,16,22,28,34,37,40,43,46,49,52,55,
                                    57,59,61,63,65,67,69,71,73,75,77,79};
    static constexpr int EXc[24] = {0,56,64,72,80,82,84,86,88,90,92,94,
                                    94,94,94,94,94,94,94,94,94,94,94,94};
    const int b = blockIdx.x & 1;
    int rb = blockIdx.x >> 1;
    int p = 0, base = 0, colg = 0, exb = 0;
#pragma unroll
    for (int i = 1; i < 24; ++i)
        if (rb >= MCc[i]) { p = i; base = MCc[i]; colg = CGc[i]; exb = EXc[i]; }
    rb -= base;

    int col = 0, nch = 0;
    for (int c = T_nc[p] - 1; c >= 0; --c) {
        int nb, ta, n;
        col_geom(p, c, nb, ta, n);
        const int nc2 = (n + 7) >> 3;
        if (nc2 > 1) {
            if (rb == 0) { col = c; nch = nc2; break; }
            --rb;
        }
        ++colg; exb += nc2 - 1;
    }
    const int h = T_h[p], g = T_g[p];
    const int s = (h == 0) ? 1 : (h == 1) ? 3 : (h == 2) ? 7 : 13;
    const int LQ = T_LQ[p];
    const int colid = b * 81 + colg;
    const float c2 = 0.09016844f;

    const int t = threadIdx.x;
    const int q = t >> 1, dpart = (t & 1) * 128;
    const int m = (col << 7) + q;

    float mj[8], lj[8];
#pragma unroll
    for (int j5 = 0; j5 < 8; ++j5) {
        if (j5 < nch) {
            mj[j5] = mlbuf[(size_t)((colid * 8 + j5) * 256) + q * 2];
            lj[j5] = mlbuf[(size_t)((colid * 8 + j5) * 256) + q * 2 + 1];
        } else { mj[j5] = -3.0e38f; lj[j5] = 0.0f; }
    }
    float M = -3.0e38f;
#pragma unroll
    for (int j5 = 0; j5 < 8; ++j5) if (j5 < nch) M = fmaxf(M, mj[j5]);
    float L = 0.0f, al[8];
#pragma unroll
    for (int j5 = 0; j5 < 8; ++j5) {
        al[j5] = (j5 < nch) ? __builtin_amdgcn_exp2f((mj[j5] - M) * c2) : 0.0f;
        L += lj[j5] * al[j5];
    }
    const float inv = (L > 0.0f) ? 1.0f / L : 0.0f;
#pragma unroll
    for (int j5 = 0; j5 < 8; ++j5) al[j5] *= inv;

    u16* dst = attnb + ((size_t)(b * 2048 + g + m * s)) * 1024 + h * 256 + dpart;

    for (int ss = 0; ss < 4; ++ss) {
        float acc32[32];
#pragma unroll
        for (int e = 0; e < 32; ++e) acc32[e] = 0.0f;
#pragma unroll
        for (int j5 = 0; j5 < 8; ++j5) {
            if (j5 >= nch) continue;
            const u16* src = (j5 == 0)
                ? (dst + ss * 32)
                : (partO_addr_c(partLo, partHi, b * 94 + exb + j5 - 1) + (size_t)q * 256 + dpart + ss * 32);
            const float sc = al[j5];
#pragma unroll
            for (int w4 = 0; w4 < 4; ++w4) {
                const uint4 pk = *(const uint4*)(src + w4 * 8);
                const u32 ww[4] = { pk.x, pk.y, pk.z, pk.w };
#pragma unroll
                for (int e = 0; e < 4; ++e) {
                    union { u32 u; float f; } lo2, hi2;
                    lo2.u = ww[e] << 16;
                    hi2.u = ww[e] & 0xffff0000u;
                    acc32[w4 * 8 + e * 2]     += sc * lo2.f;
                    acc32[w4 * 8 + e * 2 + 1] += sc * hi2.f;
                }
            }
        }
        if (m < LQ) {
#pragma unroll
            for (int w4 = 0; w4 < 4; ++w4) {
                uint4 pk;
                pk.x = (u32)f2bf(acc32[w4 * 8 + 0]) | ((u32)f2bf(acc32[w4 * 8 + 1]) << 16);
                pk.y = (u32)f2bf(acc32[w4 * 8 + 2]) | ((u32)f2bf(acc32[w4 * 8 + 3]) << 16);
                pk.z = (u32)f2bf(acc32[w4 * 8 + 4]) | ((u32)f2bf(acc32[w4 * 8 + 5]) << 16);
                pk.w = (u32)f2bf(acc32[w4 * 8 + 6]) | ((u32)f2bf(acc32[w4 * 8 + 7]) << 16);
                *(uint4*)(dst + ss * 32 + w4 * 8) = pk;
            }
        }
    }
}

// ---------------- output GEMM: out = attnb @ Wo^T + bo (f32) ----------------
__global__ __launch_bounds__(256, 3)
void gemm_out(const u16* __restrict__ A, const u16* __restrict__ Bw,
              const float* __restrict__ bias, float* __restrict__ outp) {
    __shared__ __align__(16) u16 As[2][4096], Bs[2][2048];
    const int bid = blockIdx.x;
    const int m0 = (bid >> 4) * 128;
    const int n0 = (bid & 15) * 64;
    const int t = threadIdx.x;
    const int lane = t & 63;
    const int wid = t >> 6;
    const int wr = wid >> 1, wc = wid & 1;
    const int l15 = lane & 15, l4 = lane >> 4;

    f32x4 acc[4][2] = {};

    auto stage = [&](int buf, int kt) {
        const int kbase = kt * 32;
#pragma unroll
        for (int c2 = 0; c2 < 2; ++c2) {
            const int pp = c2 * 4096 + t * 16;
            g2l16(A + (size_t)(m0 + (pp >> 6)) * 1024 + kbase + ((pp & 63) >> 1), (char*)As[buf] + pp);
        }
        const int pb = t * 16;
        g2l16(Bw + (size_t)(n0 + (pb >> 6)) * 1024 + kbase + ((pb & 63) >> 1), (char*)Bs[buf] + pb);
    };

    stage(0, 0);
    asm volatile("s_waitcnt vmcnt(0)" ::: "memory");
    __syncthreads();

    int cur = 0;
    for (int kt = 0; kt < 32; ++kt) {
        if (kt + 1 < 32) stage(cur ^ 1, kt + 1);
        bf16x8 af[4], bfr[2];
#pragma unroll
        for (int mi = 0; mi < 4; ++mi)
            af[mi] = *(const bf16x8*)((const char*)As[cur] + (wr * 64 + mi * 16 + l15) * 64 + l4 * 16);
#pragma unroll
        for (int ni = 0; ni < 2; ++ni)
            bfr[ni] = *(const bf16x8*)((const char*)Bs[cur] + (wc * 32 + ni * 16 + l15) * 64 + l4 * 16);
        __builtin_amdgcn_s_setprio(1);
#pragma unroll
        for (int mi = 0; mi < 4; ++mi)
#pragma unroll
            for (int ni = 0; ni < 2; ++ni)
                acc[mi][ni] = __builtin_amdgcn_mfma_f32_16x16x32_bf16(af[mi], bfr[ni], acc[mi][ni], 0, 0, 0);
        __builtin_amdgcn_s_setprio(0);
        asm volatile("s_waitcnt vmcnt(0)" ::: "memory");
        __syncthreads();
        cur ^= 1;
    }

    const int mbase = m0 + wr * 64 + l4 * 4;
    const int nbase = n0 + wc * 32 + l15;
#pragma unroll
    for (int ni = 0; ni < 2; ++ni) {
        const int n = nbase + ni * 16;
        const float bv = bias[n];
#pragma unroll
        for (int mi = 0; mi < 4; ++mi) {
            const int mrow = mbase + mi * 16;
#pragma unroll
            for (int r = 0; r < 4; ++r)
                outp[(size_t)(mrow + r) * 1024 + n] = acc[mi][ni][r] + bv;
        }
    }
}

extern "C" void kernel_launch(void* const* d_in, const int* in_sizes, int n_in,
                              void* d_out, int out_size, void* d_ws, size_t ws_size,
                              hipStream_t stream) {
    const float* x   = (const float*)d_in[0];
    const float* Wqk = (const float*)d_in[1];
    const float* bqk = (const float*)d_in[2];
    const float* Wv  = (const float*)d_in[3];
    const float* bv  = (const float*)d_in[4];
    const float* Wo  = (const float*)d_in[5];
    const float* bo  = (const float*)d_in[6];
    float* out = (float*)d_out;

    u16* ws     = (u16*)d_ws;
    u16* xb     = ws;             // 4,194,304 (dead after gemm_qkv -> attnb overlay)
    u16* wqkb   = ws + 4194304;   // 1,048,576 (dead after gemm_qkv -> partHi overlay)
    u16* wvb    = ws + 5242880;   // 1,048,576 (dead after gemm_qkv)
    u16* wob    = ws + 6291456;   // 1,048,576 (live until gemm_out)
    u16* kpack  = ws + 15728640;  // 4,341,760
    u16* vpack  = ws + 20070400;  // 4,341,760 (ends 24,412,160 u16 = 48.8 MB)
    u16* attnb  = ws;             // overlays xb
    u16* partLo = ws + 7340032;   // 128 slots x 32768 u16
    u16* partHi = ws + 4194304;   // 60 slots (overlays wqkb+wvb)
    float* mlbuf = (float*)d_out; // d_out dead until gemm_out

    cvt_kernel<<<7168, 256, 0, stream>>>(x, Wqk, Wv, Wo, ws);
    gemm_qkv<<<512, 256, 0, stream>>>(xb, wqkb, wvb, bqk, bv, kpack, vpack);
    attn_kernel<<<392, 256, 0, stream>>>(kpack, vpack, attnb, partLo, partHi, mlbuf);
    combine_kernel<<<80, 256, 0, stream>>>(partLo, partHi, mlbuf, attnb);
    gemm_out<<<512, 256, 0, stream>>>(attnb, wob, bo, out);
}

// Round 11
// 121.835 us; speedup vs baseline: 1.0801x; 1.0801x over previous
//
#include <hip/hip_runtime.h>
#include <cstdint>
#include <cstddef>

typedef unsigned short u16;
typedef uint32_t u32;
typedef __bf16 bf16x8 __attribute__((ext_vector_type(8)));
typedef float f32x4 __attribute__((ext_vector_type(4)));
typedef float f32x16 __attribute__((ext_vector_type(16)));

typedef __attribute__((address_space(1))) void gvoid;
typedef __attribute__((address_space(3))) void lvoid;

__device__ __forceinline__ void g2l16(const void* g, void* l) {
    __builtin_amdgcn_global_load_lds((gvoid*)g, (lvoid*)l, 16, 0, 0);
}

__device__ __forceinline__ u16 f2bf(float f) {
    union { float f; uint32_t u; } v;
    v.f = f;
    uint32_t r = (v.u + 0x7FFFu + ((v.u >> 16) & 1u)) >> 16;
    return (u16)r;
}

// ================= compressed-class problem tables (per batch: 24 problems) ==============
__device__ const int T_h[24]  = {0, 1,1,1, 2,2,2,2,2,2,2, 3,3,3,3,3,3,3,3,3,3,3,3,3};
__device__ const int T_g[24]  = {0, 0,1,2, 0,1,2,3,4,5,6, 0,1,2,3,4,5,6,7,8,9,10,11,12};
__device__ const int T_qt[24] = {0, 64,86,108, 130,140,150,160,170,180,190,
                                 200,205,210,215,220,225,230,235,240,245,250,255,260};
__device__ const int T_LQ[24] = {2048, 683,683,682, 293,293,293,293,292,292,292,
                                 158,158,158,158,158,158,158,157,157,157,157,157,157};
__device__ const int T_ktB[24]= {0, 64,86,108, 140,150,160,170,180,190,130,
                                 245,250,255,260,200,205,210,215,220,225,230,235,240};
__device__ const int T_LkB[24]= {2048, 683,683,682, 293,293,293,292,292,292,293,
                                 157,157,157,157,158,158,158,158,158,158,158,157,157};
__device__ const int T_cB[24] = {1, -341,-341,-341, -146,-146,-146,-146,-146,-146,-145,
                                 -79,-79,-79,-79,-78,-78,-78,-78,-78,-78,-78,-78,-78};
__device__ const int T_ktA[24]= {0, 108,64,86, 180,190,130,140,150,160,170,
                                 215,220,225,230,235,240,245,250,255,260,200,205,210};
__device__ const int T_LkA[24]= {0, 682,683,683, 292,292,293,293,293,293,292,
                                 158,158,158,158,157,157,157,157,157,157,158,158,158};
__device__ const int T_cA[24] = {0, -342,-341,-341, -147,-147,-146,-146,-146,-146,-146,
                                 -79,-79,-79,-79,-79,-79,-79,-79,-79,-79,-78,-78,-78};
__device__ const int T_dA[24] = {0, 0,1,1, 0,0,1,1,1,1,1, 0,0,0,0,0,0,0,0,0,0,1,1,1};
__device__ const int T_nc[24] = {16, 6,6,6, 3,3,3,3,3,3,3, 2,2,2,2,2,2,2,2,2,2,2,2,2};

__device__ __forceinline__ void col_geom(int p, int c, int& ntB, int& tA0, int& nt) {
    const int LQ = T_LQ[p];
    const int Mc = c << 7;
    int mmax = Mc + 128; if (mmax > LQ) mmax = LQ; mmax -= 1;
    int jB = mmax + T_cB[p];
    if (jB < 0) jB = 0;
    if (jB > T_LkB[p]) jB = T_LkB[p];
    ntB = (jB + 31) >> 5;
    int jlo = Mc + T_cA[p]; if (jlo < 0) jlo = 0;
    int jhi = mmax + T_dA[p];
    if (jhi > T_LkA[p]) jhi = T_LkA[p];
    tA0 = jlo >> 5;
    int ntA = 0;
    if (jhi > jlo) ntA = ((jhi + 31) >> 5) - tA0;
    nt = ntB + ntA;
}

__device__ __forceinline__ u16* partO_addr(u16* lo, u16* hi, int slot) {
    return (slot < 128) ? (lo + (size_t)slot * 32768) : (hi + (size_t)(slot - 128) * 32768);
}
__device__ __forceinline__ const u16* partO_addr_c(const u16* lo, const u16* hi, int slot) {
    return (slot < 128) ? (lo + (size_t)slot * 32768) : (hi + (size_t)(slot - 128) * 32768);
}

// ---------------- fp32 -> bf16 conversion of x, Wqk, Wv, Wo into ws ----------------
__global__ __launch_bounds__(256)
void cvt_kernel(const float* __restrict__ x, const float* __restrict__ wqk,
                const float* __restrict__ wv, const float* __restrict__ wo,
                u16* __restrict__ out) {
    int i = (blockIdx.x * 256 + threadIdx.x) * 4;
    const float* src;
    int off;
    if (i < 4194304)      { src = x;   off = 0; }
    else if (i < 5242880) { src = wqk; off = 4194304; }
    else if (i < 6291456) { src = wv;  off = 5242880; }
    else                  { src = wo;  off = 6291456; }
    float4 v = *(const float4*)(src + (i - off));
    ushort4 o;
    o.x = f2bf(v.x); o.y = f2bf(v.y); o.z = f2bf(v.z); o.w = f2bf(v.w);
    *(ushort4*)(out + i) = o;
}

// ---------------- fused QK+V projection GEMM, row-major bf16 outputs ----------------
// XCD-grouped panel map: xcd=bid&7 owns m-panels xcd*4..+3 (1MB A set L2-resident),
// n-panel = slot>>2 reused 4x back-to-back.
__global__ __launch_bounds__(256, 3)
void gemm_qkv(const u16* __restrict__ A, const u16* __restrict__ Bq, const u16* __restrict__ Bv,
              const float* __restrict__ bq, const float* __restrict__ bv,
              u16* __restrict__ qkb, u16* __restrict__ vb) {
    __shared__ __align__(16) u16 As[2][4096], Bqs[2][2048], Bvs[2][2048];
    const int bid = blockIdx.x;
    const int xcd = bid & 7, slot = bid >> 3;
    const int m0 = (xcd * 4 + (slot & 3)) * 128;
    const int n0 = (slot >> 2) * 64;
    const int t = threadIdx.x;
    const int lane = t & 63;
    const int wid = t >> 6;
    const int wr = wid >> 1, wc = wid & 1;
    const int l15 = lane & 15, l4 = lane >> 4;

    f32x4 aq[4][2] = {}, av[4][2] = {};

    auto stage = [&](int buf, int kt) {
        const int kbase = kt * 32;
#pragma unroll
        for (int c2 = 0; c2 < 2; ++c2) {
            const int pp = c2 * 4096 + t * 16;
            g2l16(A + (size_t)(m0 + (pp >> 6)) * 1024 + kbase + ((pp & 63) >> 1), (char*)As[buf] + pp);
        }
        const int pb = t * 16;
        const int rb = pb >> 6, kb = (pb & 63) >> 1;
        g2l16(Bq + (size_t)(n0 + rb) * 1024 + kbase + kb, (char*)Bqs[buf] + pb);
        g2l16(Bv + (size_t)(n0 + rb) * 1024 + kbase + kb, (char*)Bvs[buf] + pb);
    };

    stage(0, 0);
    asm volatile("s_waitcnt vmcnt(0)" ::: "memory");
    __syncthreads();

    int cur = 0;
    for (int kt = 0; kt < 32; ++kt) {
        if (kt + 1 < 32) stage(cur ^ 1, kt + 1);
        bf16x8 af[4], bfq[2], bfv[2];
#pragma unroll
        for (int mi = 0; mi < 4; ++mi)
            af[mi] = *(const bf16x8*)((const char*)As[cur] + (wr * 64 + mi * 16 + l15) * 64 + l4 * 16);
#pragma unroll
        for (int ni = 0; ni < 2; ++ni) {
            bfq[ni] = *(const bf16x8*)((const char*)Bqs[cur] + (wc * 32 + ni * 16 + l15) * 64 + l4 * 16);
            bfv[ni] = *(const bf16x8*)((const char*)Bvs[cur] + (wc * 32 + ni * 16 + l15) * 64 + l4 * 16);
        }
        __builtin_amdgcn_s_setprio(1);
#pragma unroll
        for (int mi = 0; mi < 4; ++mi)
#pragma unroll
            for (int ni = 0; ni < 2; ++ni) {
                aq[mi][ni] = __builtin_amdgcn_mfma_f32_16x16x32_bf16(af[mi], bfq[ni], aq[mi][ni], 0, 0, 0);
                av[mi][ni] = __builtin_amdgcn_mfma_f32_16x16x32_bf16(af[mi], bfv[ni], av[mi][ni], 0, 0, 0);
            }
        __builtin_amdgcn_s_setprio(0);
        asm volatile("s_waitcnt vmcnt(0)" ::: "memory");
        __syncthreads();
        cur ^= 1;
    }

    const int mbase = m0 + wr * 64 + l4 * 4;
    const int nbase = n0 + wc * 32 + l15;
#pragma unroll
    for (int ni = 0; ni < 2; ++ni) {
        const int n = nbase + ni * 16;
        const float bq_ = bq[n];
        const float bv_ = bv[n];
#pragma unroll
        for (int mi = 0; mi < 4; ++mi) {
            const int mrow = mbase + mi * 16;
#pragma unroll
            for (int r = 0; r < 4; ++r) {
                qkb[(size_t)(mrow + r) * 1024 + n] = f2bf(aq[mi][ni][r] + bq_);
                vb [(size_t)(mrow + r) * 1024 + n] = f2bf(av[mi][ni][r] + bv_);
            }
        }
    }
}

// ---------------- tile decode for repack kernel ----------------
__device__ __forceinline__ void tile_decode(int tt, int& h, int& cls, int& jt, int& LK) {
    if (tt < 64)       { h = 0; cls = 0;               jt = tt;              LK = 2048; }
    else if (tt < 130) { h = 1; cls = (tt - 64) / 22;  jt = (tt - 64) % 22;  LK = (cls < 2) ? 683 : 682; }
    else if (tt < 200) { h = 2; cls = (tt - 130) / 10; jt = (tt - 130) % 10; LK = (cls < 4) ? 293 : 292; }
    else               { h = 3; cls = (tt - 200) / 5;  jt = (tt - 200) % 5;  LK = (cls < 7) ? 158 : 157; }
}

// ---------------- repack K and V into fragment-major class-tile layouts (merged) ---------
__global__ __launch_bounds__(256)
void repack_kv(const u16* __restrict__ qkb, const u16* __restrict__ vb,
               u16* __restrict__ kpack, u16* __restrict__ vpack) {
    __shared__ __align__(16) unsigned char sm[32768];   // K 16KB | V 16KB
    const int bid = blockIdx.x;
    const int b = bid & 1;
    const int tt = bid >> 1;
    int h, cls, jt, LK;
    tile_decode(tt, h, cls, jt, LK);
    const int s = (h == 0) ? 1 : (h == 1) ? 3 : (h == 2) ? 7 : 13;
    const int j0 = jt * 32;
    int nval = LK - j0; if (nval > 32) nval = 32;
    const int t = threadIdx.x;

#pragma unroll
    for (int i2 = 0; i2 < 4; ++i2) {
        const int p = i2 * 4096 + t * 16;
        const int j = p >> 9;
        const int cb = (p & 511) ^ ((j & 31) << 4);
        const int jj = (j < nval) ? j : (nval - 1);
        const size_t gofs = (size_t)((b * 2048 + cls + (j0 + jj) * s) * 1024 + h * 256) + (cb >> 1);
        g2l16(qkb + gofs, sm + p);
        g2l16(vb  + gofs, sm + 16384 + p);
    }
    asm volatile("s_waitcnt vmcnt(0)" ::: "memory");
    __syncthreads();
    if (nval < 32) {
        const int pb = 16384 + nval * 512;
        for (int off = pb + t * 16; off < 32768; off += 4096) {
            uint4 z; z.x = 0; z.y = 0; z.z = 0; z.w = 0;
            *(uint4*)(sm + off) = z;
        }
        __syncthreads();
    }
    const size_t tb = (size_t)(b * 265 + tt) * 8192;
    // kpack: 8 consecutive elems = same j, d0..d0+7
#pragma unroll
    for (int i2 = 0; i2 < 4; ++i2) {
        const int o = (i2 * 256 + t) * 8;
        const int dc = o >> 9;
        const int idx = (o >> 3) & 63;
        const int j = idx & 31;
        const int d0 = dc * 16 + (idx >> 5) * 8;
        const uint4 pk = *(const uint4*)(sm + j * 512 + ((d0 * 2) ^ ((j & 31) << 4)));
        *(uint4*)(kpack + tb + o) = pk;
    }
    // vpack: transposed gather from LDS
#pragma unroll
    for (int i2 = 0; i2 < 4; ++i2) {
        const int o = (i2 * 256 + t) * 8;
        const int slot2 = o >> 9;
        const int idx = (o >> 3) & 63;
        const int jb = (slot2 >> 3) * 16 + (idx >> 5) * 8;
        const int d = (slot2 & 7) * 32 + (idx & 31);
        u32 wpk[4];
#pragma unroll
        for (int e2 = 0; e2 < 4; ++e2) {
            const int j1 = jb + e2 * 2, j2 = j1 + 1;
            const u16 a0 = *(const u16*)(sm + 16384 + j1 * 512 + (((d >> 3) ^ (j1 & 31)) << 4) + (d & 7) * 2);
            const u16 a1 = *(const u16*)(sm + 16384 + j2 * 512 + (((d >> 3) ^ (j2 & 31)) << 4) + (d & 7) * 2);
            wpk[e2] = (u32)a0 | ((u32)a1 << 16);
        }
        uint4 pk; pk.x = wpk[0]; pk.y = wpk[1]; pk.z = wpk[2]; pk.w = wpk[3];
        *(uint4*)(vpack + tb + o) = pk;
    }
}

// ---------------- compressed flash attention: XCD-pinned, LDS double-buffered ----------
__global__ __launch_bounds__(256, 2)
void attn_kernel(const u16* __restrict__ kpack, const u16* __restrict__ vpack,
                 u16* __restrict__ attnb, u16* __restrict__ partLo, u16* __restrict__ partHi,
                 float* __restrict__ mlbuf) {
    __shared__ __align__(16) unsigned char sm[65536];
    static constexpr int CGc[24] = {0,16,22,28,34,37,40,43,46,49,52,55,
                                    57,59,61,63,65,67,69,71,73,75,77,79};
    static constexpr int EXc[24] = {0,56,64,72,80,82,84,86,88,90,92,94,
                                    94,94,94,94,94,94,94,94,94,94,94,94};
    static constexpr int Tpc[24] = {72,14,14,14,5,5,5,5,5,5,5,2,2,2,2,2,2,2,2,2,2,2,2,2};

    const int bid = blockIdx.x;
    const int xcd = bid & 7, slot = bid >> 3;
    const int b = xcd & 1, quad = xcd >> 1;
    int hsel, hcb;
    if (quad <= 1) {
        if (slot < 36)      { hsel = 0; hcb = quad * 36 + slot; }
        else if (slot < 49) { hsel = 3; hcb = quad * 13 + (slot - 36); }
        else return;
    } else if (quad == 2) {
        if (slot >= 42) return;
        hsel = 1; hcb = slot;
    } else {
        if (slot >= 35) return;
        hsel = 2; hcb = slot;
    }
    int p = (hsel == 0) ? 0 : (hsel == 1) ? 1 : (hsel == 2) ? 4 : 11;
    int rb = hcb;
    while (rb >= Tpc[p]) { rb -= Tpc[p]; ++p; }
    int colg = CGc[p], exb = EXc[p];

    const int LQ = T_LQ[p];
    const int cB = T_cB[p], cA = T_cA[p], dA = T_dA[p];
    const int LKB = T_LkB[p], LKA = T_LkA[p];
    const int ktB = T_ktB[p], ktA = T_ktA[p];
    const int h = T_h[p], g = T_g[p], nc = T_nc[p], qt0 = T_qt[p];
    const int s = (h == 0) ? 1 : (h == 1) ? 3 : (h == 2) ? 7 : 13;

    int col = 0, chunk = 0, ntB = 0, tA0 = 0, nt = 0;
    for (int c = nc - 1; c >= 0; --c) {
        const int Mc = c << 7;
        int mmax = Mc + 128; if (mmax > LQ) mmax = LQ; mmax -= 1;
        int jB = mmax + cB; if (jB < 0) jB = 0; if (jB > LKB) jB = LKB;
        const int nb = (jB + 31) >> 5;
        int jlo = Mc + cA; if (jlo < 0) jlo = 0;
        int jhi = mmax + dA; if (jhi > LKA) jhi = LKA;
        const int ta = jlo >> 5;
        const int na = (jhi > jlo) ? (((jhi + 31) >> 5) - ta) : 0;
        const int n = nb + na;
        const int nch2 = (n + 7) >> 3;
        if (rb < nch2) { col = c; chunk = rb; ntB = nb; tA0 = ta; nt = n; break; }
        rb -= nch2; ++colg; exb += nch2 - 1;
    }
    const int nch = (nt + 7) >> 3;
    const int PBi = b * 265;

    const int t = threadIdx.x;
    const int w = t >> 6;
    const int l = t & 63;
    const int l31 = l & 31, h5 = l >> 5;
    const int m = (col << 7) + (w << 5) + l31;     // compressed query index
    const float c2 = 0.09016844f;                  // (1/16) * log2(e)
    const int lane16 = l * 16;                     // byte offset in packed tile

    // Q fragments from kpack class-g list tile (coalesced)
    bf16x8 qf[16];
    {
        const u16* qb = kpack + (size_t)(PBi + qt0 + col * 4 + w) * 8192 + l * 8;
#pragma unroll
        for (int dc = 0; dc < 16; ++dc)
            qf[dc] = *(const bf16x8*)(qb + dc * 512);
    }

    auto tileof = [&](int tv) -> int {
        return (tv < ntB) ? (ktB + tv) : (ktA + tA0 + (tv - ntB));
    };
    auto stage = [&](int tv, int buf) {
        const size_t tb = (size_t)(PBi + tileof(tv)) * 8192;
        unsigned char* Kd = sm + buf * 32768;
        unsigned char* Vd = Kd + 16384;
#pragma unroll
        for (int i2 = 0; i2 < 4; ++i2) {
            const int off = i2 * 4096 + t * 16;
            g2l16(kpack + tb + (off >> 1), Kd + off);
            g2l16(vpack + tb + (off >> 1), Vd + off);
        }
    };

    const int tt0 = chunk * 8;
    int tt1 = tt0 + 8; if (tt1 > nt) tt1 = nt;

    f32x16 o[8] = {};
    float mrun = -3.0e38f, lrun = 0.0f;

    stage(tt0, 0);
    asm volatile("s_waitcnt vmcnt(0)" ::: "memory");
    __syncthreads();

    int buf = 0;
    for (int tv = tt0; tv < tt1; ++tv) {
        if (tv + 1 < tt1) stage(tv + 1, buf ^ 1);

        int j0, lo, hi;
        if (tv < ntB) { j0 = tv << 5; lo = -100000; hi = cB; }
        else { const int ta = tA0 + tv - ntB; j0 = ta << 5; lo = cA; hi = dA; }

        const unsigned char* Kb = sm + buf * 32768;
        const unsigned char* Vb = Kb + 16384;

        // S^T = K * Q^T
        f32x16 sacc = {};
        __builtin_amdgcn_s_setprio(1);
#pragma unroll
        for (int dc = 0; dc < 16; ++dc) {
            const bf16x8 kf = *(const bf16x8*)(Kb + dc * 1024 + lane16);
            sacc = __builtin_amdgcn_mfma_f32_32x32x16_bf16(kf, qf[dc], sacc, 0, 0, 0);
        }
        __builtin_amdgcn_s_setprio(0);

        // mask + online softmax, in place (lane-local; e = j - m)
        const int ebase = j0 - m;
        float tmax = -3.0e38f;
#pragma unroll
        for (int r = 0; r < 16; ++r) {
            const int km = (r & 3) + 8 * (r >> 2) + 4 * h5;
            const int e = ebase + km;
            const bool ok = (e >= lo) && (e < hi);
            sacc[r] = ok ? sacc[r] : -3.0e38f;
            tmax = fmaxf(tmax, sacc[r]);
        }
        tmax = fmaxf(tmax, __shfl_xor(tmax, 32, 64));
        if (!__all(tmax <= mrun + 8.0f)) {     // defer-max
            const float mnew = fmaxf(mrun, tmax);
            const float fsc = __builtin_amdgcn_exp2f((mrun - mnew) * c2);
            lrun *= fsc;
#pragma unroll
            for (int ch = 0; ch < 8; ++ch)
#pragma unroll
                for (int r = 0; r < 16; ++r)
                    o[ch][r] *= fsc;
            mrun = mnew;
        }
        float psum = 0.0f;
#pragma unroll
        for (int r = 0; r < 16; ++r) {
            const float pv = (sacc[r] > -1.0e37f) ? __builtin_amdgcn_exp2f((sacc[r] - mrun) * c2) : 0.0f;
            sacc[r] = pv;
            psum += pv;
        }
        lrun += psum;

        // P -> bf16 fragments: cvt_pk + permlane32_swap
        uint32_t w0, w1, w2, w3, w4, w5, w6, w7;
        asm("v_cvt_pk_bf16_f32 %0,%1,%2" : "=v"(w0) : "v"(sacc[0]),  "v"(sacc[1]));
        asm("v_cvt_pk_bf16_f32 %0,%1,%2" : "=v"(w1) : "v"(sacc[2]),  "v"(sacc[3]));
        asm("v_cvt_pk_bf16_f32 %0,%1,%2" : "=v"(w2) : "v"(sacc[4]),  "v"(sacc[5]));
        asm("v_cvt_pk_bf16_f32 %0,%1,%2" : "=v"(w3) : "v"(sacc[6]),  "v"(sacc[7]));
        asm("v_cvt_pk_bf16_f32 %0,%1,%2" : "=v"(w4) : "v"(sacc[8]),  "v"(sacc[9]));
        asm("v_cvt_pk_bf16_f32 %0,%1,%2" : "=v"(w5) : "v"(sacc[10]), "v"(sacc[11]));
        asm("v_cvt_pk_bf16_f32 %0,%1,%2" : "=v"(w6) : "v"(sacc[12]), "v"(sacc[13]));
        asm("v_cvt_pk_bf16_f32 %0,%1,%2" : "=v"(w7) : "v"(sacc[14]), "v"(sacc[15]));
        asm("v_permlane32_swap_b32 %0, %1" : "+v"(w0), "+v"(w2));
        asm("v_permlane32_swap_b32 %0, %1" : "+v"(w1), "+v"(w3));
        asm("v_permlane32_swap_b32 %0, %1" : "+v"(w4), "+v"(w6));
        asm("v_permlane32_swap_b32 %0, %1" : "+v"(w5), "+v"(w7));
        union { uint32_t u[4]; bf16x8 v; } p0u, p1u;
        p0u.u[0] = w0; p0u.u[1] = w1; p0u.u[2] = w2; p0u.u[3] = w3;
        p1u.u[0] = w4; p1u.u[1] = w5; p1u.u[2] = w6; p1u.u[3] = w7;

        // O^T += V^T * P^T
        __builtin_amdgcn_s_setprio(1);
#pragma unroll
        for (int kk = 0; kk < 2; ++kk) {
            const bf16x8 pf = kk ? p1u.v : p0u.v;
#pragma unroll
            for (int ch = 0; ch < 8; ++ch) {
                const bf16x8 vf = *(const bf16x8*)(Vb + (kk * 8 + ch) * 1024 + lane16);
                o[ch] = __builtin_amdgcn_mfma_f32_32x32x16_bf16(vf, pf, o[ch], 0, 0, 0);
            }
        }
        __builtin_amdgcn_s_setprio(0);

        asm volatile("s_waitcnt vmcnt(0)" ::: "memory");
        __syncthreads();
        buf ^= 1;
    }

    lrun += __shfl_xor(lrun, 32, 64);

    float scale = 1.0f;
    u16* ab;
    const int qm = (w << 5) + l31;
    if (nch == 1) {
        scale = (lrun > 0.0f) ? 1.0f / lrun : 0.0f;
        ab = attnb + ((size_t)(b * 2048 + g + m * s)) * 1024 + h * 256;
    } else {
        if (h5 == 0 && m < LQ) {
            const int colid = b * 81 + colg;
            mlbuf[(size_t)((colid * 8 + chunk) * 256) + qm * 2]     = mrun;
            mlbuf[(size_t)((colid * 8 + chunk) * 256) + qm * 2 + 1] = lrun;
        }
        if (chunk == 0)
            ab = attnb + ((size_t)(b * 2048 + g + m * s)) * 1024 + h * 256;
        else
            ab = partO_addr(partLo, partHi, b * 94 + exb + chunk - 1) + (size_t)qm * 256;
    }

    if (m < LQ) {
#pragma unroll
        for (int ch = 0; ch < 8; ++ch) {
#pragma unroll
            for (int g2 = 0; g2 < 4; ++g2) {
                ushort4 wv4;
                wv4.x = f2bf(o[ch][g2 * 4 + 0] * scale);
                wv4.y = f2bf(o[ch][g2 * 4 + 1] * scale);
                wv4.z = f2bf(o[ch][g2 * 4 + 2] * scale);
                wv4.w = f2bf(o[ch][g2 * 4 + 3] * scale);
                *(ushort4*)(ab + ch * 32 + 8 * g2 + 4 * h5) = wv4;
            }
        }
    }
}

// ---------------- combine chunked columns ----------------
__global__ __launch_bounds__(256)
void combine_kernel(const u16* __restrict__ partLo, const u16* __restrict__ partHi,
                    const float* __restrict__ mlbuf, u16* __restrict__ attnb) {
    static constexpr int MCc[24] = {0,14,18,22,26,28,30,32,34,36,38,40,
                                    40,40,40,40,40,40,40,40,40,40,40,40};
    static constexpr int CGc[24] = {0,16,22,28,34,37,40,43,46,49,52,55,
                                    57,59,61,63,65,67,69,71,73,75,77,79};
    static constexpr int EXc[24] = {0,56,64,72,80,82,84,86,88,90,92,94,
                                    94,94,94,94,94,94,94,94,94,94,94,94};
    const int b = blockIdx.x & 1;
    int rb = blockIdx.x >> 1;
    int p = 0, base = 0, colg = 0, exb = 0;
#pragma unroll
    for (int i = 1; i < 24; ++i)
        if (rb >= MCc[i]) { p = i; base = MCc[i]; colg = CGc[i]; exb = EXc[i]; }
    rb -= base;

    int col = 0, nch = 0;
    for (int c = T_nc[p] - 1; c >= 0; --c) {
        int nb, ta, n;
        col_geom(p, c, nb, ta, n);
        const int nc2 = (n + 7) >> 3;
        if (nc2 > 1) {
            if (rb == 0) { col = c; nch = nc2; break; }
            --rb;
        }
        ++colg; exb += nc2 - 1;
    }
    const int h = T_h[p], g = T_g[p];
    const int s = (h == 0) ? 1 : (h == 1) ? 3 : (h == 2) ? 7 : 13;
    const int LQ = T_LQ[p];
    const int colid = b * 81 + colg;
    const float c2 = 0.09016844f;

    const int t = threadIdx.x;
    const int q = t >> 1, dpart = (t & 1) * 128;
    const int m = (col << 7) + q;

    float mj[8], lj[8];
#pragma unroll
    for (int j5 = 0; j5 < 8; ++j5) {
        if (j5 < nch) {
            mj[j5] = mlbuf[(size_t)((colid * 8 + j5) * 256) + q * 2];
            lj[j5] = mlbuf[(size_t)((colid * 8 + j5) * 256) + q * 2 + 1];
        } else { mj[j5] = -3.0e38f; lj[j5] = 0.0f; }
    }
    float M = -3.0e38f;
#pragma unroll
    for (int j5 = 0; j5 < 8; ++j5) if (j5 < nch) M = fmaxf(M, mj[j5]);
    float L = 0.0f, al[8];
#pragma unroll
    for (int j5 = 0; j5 < 8; ++j5) {
        al[j5] = (j5 < nch) ? __builtin_amdgcn_exp2f((mj[j5] - M) * c2) : 0.0f;
        L += lj[j5] * al[j5];
    }
    const float inv = (L > 0.0f) ? 1.0f / L : 0.0f;
#pragma unroll
    for (int j5 = 0; j5 < 8; ++j5) al[j5] *= inv;

    u16* dst = attnb + ((size_t)(b * 2048 + g + m * s)) * 1024 + h * 256 + dpart;

    for (int ss = 0; ss < 4; ++ss) {
        float acc32[32];
#pragma unroll
        for (int e = 0; e < 32; ++e) acc32[e] = 0.0f;
#pragma unroll
        for (int j5 = 0; j5 < 8; ++j5) {
            if (j5 >= nch) continue;
            const u16* src = (j5 == 0)
                ? (dst + ss * 32)
                : (partO_addr_c(partLo, partHi, b * 94 + exb + j5 - 1) + (size_t)q * 256 + dpart + ss * 32);
            const float sc = al[j5];
#pragma unroll
            for (int w4 = 0; w4 < 4; ++w4) {
                const uint4 pk = *(const uint4*)(src + w4 * 8);
                const u32 ww[4] = { pk.x, pk.y, pk.z, pk.w };
#pragma unroll
                for (int e = 0; e < 4; ++e) {
                    union { u32 u; float f; } lo2, hi2;
                    lo2.u = ww[e] << 16;
                    hi2.u = ww[e] & 0xffff0000u;
                    acc32[w4 * 8 + e * 2]     += sc * lo2.f;
                    acc32[w4 * 8 + e * 2 + 1] += sc * hi2.f;
                }
            }
        }
        if (m < LQ) {
#pragma unroll
            for (int w4 = 0; w4 < 4; ++w4) {
                uint4 pk;
                pk.x = (u32)f2bf(acc32[w4 * 8 + 0]) | ((u32)f2bf(acc32[w4 * 8 + 1]) << 16);
                pk.y = (u32)f2bf(acc32[w4 * 8 + 2]) | ((u32)f2bf(acc32[w4 * 8 + 3]) << 16);
                pk.z = (u32)f2bf(acc32[w4 * 8 + 4]) | ((u32)f2bf(acc32[w4 * 8 + 5]) << 16);
                pk.w = (u32)f2bf(acc32[w4 * 8 + 6]) | ((u32)f2bf(acc32[w4 * 8 + 7]) << 16);
                *(uint4*)(dst + ss * 32 + w4 * 8) = pk;
            }
        }
    }
}

// ---------------- output GEMM: out = attnb @ Wo^T + bo (f32) ----------------
__global__ __launch_bounds__(256, 3)
void gemm_out(const u16* __restrict__ A, const u16* __restrict__ Bw,
              const float* __restrict__ bias, float* __restrict__ outp) {
    __shared__ __align__(16) u16 As[2][4096], Bs[2][2048];
    const int bid = blockIdx.x;
    const int xcd = bid & 7, slot = bid >> 3;
    const int m0 = (xcd * 4 + (slot & 3)) * 128;
    const int n0 = (slot >> 2) * 64;
    const int t = threadIdx.x;
    const int lane = t & 63;
    const int wid = t >> 6;
    const int wr = wid >> 1, wc = wid & 1;
    const int l15 = lane & 15, l4 = lane >> 4;

    f32x4 acc[4][2] = {};

    auto stage = [&](int buf, int kt) {
        const int kbase = kt * 32;
#pragma unroll
        for (int c2 = 0; c2 < 2; ++c2) {
            const int pp = c2 * 4096 + t * 16;
            g2l16(A + (size_t)(m0 + (pp >> 6)) * 1024 + kbase + ((pp & 63) >> 1), (char*)As[buf] + pp);
        }
        const int pb = t * 16;
        g2l16(Bw + (size_t)(n0 + (pb >> 6)) * 1024 + kbase + ((pb & 63) >> 1), (char*)Bs[buf] + pb);
    };

    stage(0, 0);
    asm volatile("s_waitcnt vmcnt(0)" ::: "memory");
    __syncthreads();

    int cur = 0;
    for (int kt = 0; kt < 32; ++kt) {
        if (kt + 1 < 32) stage(cur ^ 1, kt + 1);
        bf16x8 af[4], bfr[2];
#pragma unroll
        for (int mi = 0; mi < 4; ++mi)
            af[mi] = *(const bf16x8*)((const char*)As[cur] + (wr * 64 + mi * 16 + l15) * 64 + l4 * 16);
#pragma unroll
        for (int ni = 0; ni < 2; ++ni)
            bfr[ni] = *(const bf16x8*)((const char*)Bs[cur] + (wc * 32 + ni * 16 + l15) * 64 + l4 * 16);
        __builtin_amdgcn_s_setprio(1);
#pragma unroll
        for (int mi = 0; mi < 4; ++mi)
#pragma unroll
            for (int ni = 0; ni < 2; ++ni)
                acc[mi][ni] = __builtin_amdgcn_mfma_f32_16x16x32_bf16(af[mi], bfr[ni], acc[mi][ni], 0, 0, 0);
        __builtin_amdgcn_s_setprio(0);
        asm volatile("s_waitcnt vmcnt(0)" ::: "memory");
        __syncthreads();
        cur ^= 1;
    }

    const int mbase = m0 + wr * 64 + l4 * 4;
    const int nbase = n0 + wc * 32 + l15;
#pragma unroll
    for (int ni = 0; ni < 2; ++ni) {
        const int n = nbase + ni * 16;
        const float bv = bias[n];
#pragma unroll
        for (int mi = 0; mi < 4; ++mi) {
            const int mrow = mbase + mi * 16;
#pragma unroll
            for (int r = 0; r < 4; ++r)
                outp[(size_t)(mrow + r) * 1024 + n] = acc[mi][ni][r] + bv;
        }
    }
}

extern "C" void kernel_launch(void* const* d_in, const int* in_sizes, int n_in,
                              void* d_out, int out_size, void* d_ws, size_t ws_size,
                              hipStream_t stream) {
    const float* x   = (const float*)d_in[0];
    const float* Wqk = (const float*)d_in[1];
    const float* bqk = (const float*)d_in[2];
    const float* Wv  = (const float*)d_in[3];
    const float* bv  = (const float*)d_in[4];
    const float* Wo  = (const float*)d_in[5];
    const float* bo  = (const float*)d_in[6];
    float* out = (float*)d_out;

    u16* ws     = (u16*)d_ws;
    u16* xb     = ws;             // 4,194,304 (dead after gemm_qkv -> attnb overlay)
    u16* wqkb   = ws + 4194304;   // 1,048,576 (dead after gemm_qkv -> partHi overlay)
    u16* wvb    = ws + 5242880;   // 1,048,576 (dead after gemm_qkv)
    u16* wob    = ws + 6291456;   // 1,048,576 (live until gemm_out)
    u16* qkb    = ws + 7340032;   // 4,194,304 (dead after repack_kv -> partLo overlay)
    u16* vb     = ws + 11534336;  // 4,194,304 (dead after repack_kv)
    u16* kpack  = ws + 15728640;  // 4,341,760
    u16* vpack  = ws + 20070400;  // 4,341,760 (ends 24,412,160 u16 = 48.8 MB)
    u16* attnb  = ws;             // overlays xb
    u16* partLo = ws + 7340032;   // 128 slots x 32768 u16 (overlays qkb)
    u16* partHi = ws + 4194304;   // 60 slots (overlays wqkb+wvb)
    float* mlbuf = (float*)d_out; // d_out dead until gemm_out

    cvt_kernel<<<7168, 256, 0, stream>>>(x, Wqk, Wv, Wo, ws);
    gemm_qkv<<<512, 256, 0, stream>>>(xb, wqkb, wvb, bqk, bv, qkb, vb);
    repack_kv<<<530, 256, 0, stream>>>(qkb, vb, kpack, vpack);
    attn_kernel<<<392, 256, 0, stream>>>(kpack, vpack, attnb, partLo, partHi, mlbuf);
    combine_kernel<<<80, 256, 0, stream>>>(partLo, partHi, mlbuf, attnb);
    gemm_out<<<512, 256, 0, stream>>>(attnb, wob, bo, out);
}

// Round 12
// 121.305 us; speedup vs baseline: 1.0848x; 1.0044x over previous
//
#include <hip/hip_runtime.h>
#include <cstdint>
#include <cstddef>

typedef unsigned short u16;
typedef uint32_t u32;
typedef __bf16 bf16x8 __attribute__((ext_vector_type(8)));
typedef float f32x4 __attribute__((ext_vector_type(4)));
typedef float f32x16 __attribute__((ext_vector_type(16)));

typedef __attribute__((address_space(1))) void gvoid;
typedef __attribute__((address_space(3))) void lvoid;

__device__ __forceinline__ void g2l16(const void* g, void* l) {
    __builtin_amdgcn_global_load_lds((gvoid*)g, (lvoid*)l, 16, 0, 0);
}

__device__ __forceinline__ u16 f2bf(float f) {
    union { float f; uint32_t u; } v;
    v.f = f;
    uint32_t r = (v.u + 0x7FFFu + ((v.u >> 16) & 1u)) >> 16;
    return (u16)r;
}

// ================= compressed-class problem tables (per batch: 24 problems) ==============
__device__ const int T_h[24]  = {0, 1,1,1, 2,2,2,2,2,2,2, 3,3,3,3,3,3,3,3,3,3,3,3,3};
__device__ const int T_g[24]  = {0, 0,1,2, 0,1,2,3,4,5,6, 0,1,2,3,4,5,6,7,8,9,10,11,12};
__device__ const int T_qt[24] = {0, 64,86,108, 130,140,150,160,170,180,190,
                                 200,205,210,215,220,225,230,235,240,245,250,255,260};
__device__ const int T_LQ[24] = {2048, 683,683,682, 293,293,293,293,292,292,292,
                                 158,158,158,158,158,158,158,157,157,157,157,157,157};
__device__ const int T_ktB[24]= {0, 64,86,108, 140,150,160,170,180,190,130,
                                 245,250,255,260,200,205,210,215,220,225,230,235,240};
__device__ const int T_LkB[24]= {2048, 683,683,682, 293,293,293,292,292,292,293,
                                 157,157,157,157,158,158,158,158,158,158,158,157,157};
__device__ const int T_cB[24] = {1, -341,-341,-341, -146,-146,-146,-146,-146,-146,-145,
                                 -79,-79,-79,-79,-78,-78,-78,-78,-78,-78,-78,-78,-78};
__device__ const int T_ktA[24]= {0, 108,64,86, 180,190,130,140,150,160,170,
                                 215,220,225,230,235,240,245,250,255,260,200,205,210};
__device__ const int T_LkA[24]= {0, 682,683,683, 292,292,293,293,293,293,292,
                                 158,158,158,158,157,157,157,157,157,157,158,158,158};
__device__ const int T_cA[24] = {0, -342,-341,-341, -147,-147,-146,-146,-146,-146,-146,
                                 -79,-79,-79,-79,-79,-79,-79,-79,-79,-79,-78,-78,-78};
__device__ const int T_dA[24] = {0, 0,1,1, 0,0,1,1,1,1,1, 0,0,0,0,0,0,0,0,0,0,1,1,1};
__device__ const int T_nc[24] = {16, 6,6,6, 3,3,3,3,3,3,3, 2,2,2,2,2,2,2,2,2,2,2,2,2};

__device__ __forceinline__ void col_geom(int p, int c, int& ntB, int& tA0, int& nt) {
    const int LQ = T_LQ[p];
    const int Mc = c << 7;
    int mmax = Mc + 128; if (mmax > LQ) mmax = LQ; mmax -= 1;
    int jB = mmax + T_cB[p];
    if (jB < 0) jB = 0;
    if (jB > T_LkB[p]) jB = T_LkB[p];
    ntB = (jB + 31) >> 5;
    int jlo = Mc + T_cA[p]; if (jlo < 0) jlo = 0;
    int jhi = mmax + T_dA[p];
    if (jhi > T_LkA[p]) jhi = T_LkA[p];
    tA0 = jlo >> 5;
    int ntA = 0;
    if (jhi > jlo) ntA = ((jhi + 31) >> 5) - tA0;
    nt = ntB + ntA;
}

__device__ __forceinline__ u16* partO_addr(u16* lo, u16* hi, int slot) {
    return (slot < 128) ? (lo + (size_t)slot * 32768) : (hi + (size_t)(slot - 128) * 32768);
}
__device__ __forceinline__ const u16* partO_addr_c(const u16* lo, const u16* hi, int slot) {
    return (slot < 128) ? (lo + (size_t)slot * 32768) : (hi + (size_t)(slot - 128) * 32768);
}

// ---------------- fp32 -> bf16 conversion of x, Wqk, Wv, Wo into ws ----------------
__global__ __launch_bounds__(256)
void cvt_kernel(const float* __restrict__ x, const float* __restrict__ wqk,
                const float* __restrict__ wv, const float* __restrict__ wo,
                u16* __restrict__ out) {
    int i = (blockIdx.x * 256 + threadIdx.x) * 4;
    const float* src;
    int off;
    if (i < 4194304)      { src = x;   off = 0; }
    else if (i < 5242880) { src = wqk; off = 4194304; }
    else if (i < 6291456) { src = wv;  off = 5242880; }
    else                  { src = wo;  off = 6291456; }
    float4 v = *(const float4*)(src + (i - off));
    ushort4 o;
    o.x = f2bf(v.x); o.y = f2bf(v.y); o.z = f2bf(v.z); o.w = f2bf(v.w);
    *(ushort4*)(out + i) = o;
}

// ---------------- fused QK+V projection GEMM, row-major bf16 outputs ----------------
// 2-D XCD map: xcd = (m-group 0..3) x (n-half 0..1). Per-XCD L2 set = 8 A-panels (2MB)
// + half of Bq/Bv (2MB) = 4MB.
__global__ __launch_bounds__(256, 3)
void gemm_qkv(const u16* __restrict__ A, const u16* __restrict__ Bq, const u16* __restrict__ Bv,
              const float* __restrict__ bq, const float* __restrict__ bv,
              u16* __restrict__ qkb, u16* __restrict__ vb) {
    __shared__ __align__(16) u16 As[2][4096], Bqs[2][2048], Bvs[2][2048];
    const int bid = blockIdx.x;
    const int xcd = bid & 7, slot = bid >> 3;
    const int m0 = ((xcd >> 1) * 8 + (slot & 7)) * 128;
    const int n0 = ((xcd & 1) * 8 + (slot >> 3)) * 64;
    const int t = threadIdx.x;
    const int lane = t & 63;
    const int wid = t >> 6;
    const int wr = wid >> 1, wc = wid & 1;
    const int l15 = lane & 15, l4 = lane >> 4;

    f32x4 aq[4][2] = {}, av[4][2] = {};

    auto stage = [&](int buf, int kt) {
        const int kbase = kt * 32;
#pragma unroll
        for (int c2 = 0; c2 < 2; ++c2) {
            const int pp = c2 * 4096 + t * 16;
            g2l16(A + (size_t)(m0 + (pp >> 6)) * 1024 + kbase + ((pp & 63) >> 1), (char*)As[buf] + pp);
        }
        const int pb = t * 16;
        const int rb = pb >> 6, kb = (pb & 63) >> 1;
        g2l16(Bq + (size_t)(n0 + rb) * 1024 + kbase + kb, (char*)Bqs[buf] + pb);
        g2l16(Bv + (size_t)(n0 + rb) * 1024 + kbase + kb, (char*)Bvs[buf] + pb);
    };

    stage(0, 0);
    asm volatile("s_waitcnt vmcnt(0)" ::: "memory");
    __syncthreads();

    int cur = 0;
    for (int kt = 0; kt < 32; ++kt) {
        if (kt + 1 < 32) stage(cur ^ 1, kt + 1);
        bf16x8 af[4], bfq[2], bfv[2];
#pragma unroll
        for (int mi = 0; mi < 4; ++mi)
            af[mi] = *(const bf16x8*)((const char*)As[cur] + (wr * 64 + mi * 16 + l15) * 64 + l4 * 16);
#pragma unroll
        for (int ni = 0; ni < 2; ++ni) {
            bfq[ni] = *(const bf16x8*)((const char*)Bqs[cur] + (wc * 32 + ni * 16 + l15) * 64 + l4 * 16);
            bfv[ni] = *(const bf16x8*)((const char*)Bvs[cur] + (wc * 32 + ni * 16 + l15) * 64 + l4 * 16);
        }
        __builtin_amdgcn_s_setprio(1);
#pragma unroll
        for (int mi = 0; mi < 4; ++mi)
#pragma unroll
            for (int ni = 0; ni < 2; ++ni) {
                aq[mi][ni] = __builtin_amdgcn_mfma_f32_16x16x32_bf16(af[mi], bfq[ni], aq[mi][ni], 0, 0, 0);
                av[mi][ni] = __builtin_amdgcn_mfma_f32_16x16x32_bf16(af[mi], bfv[ni], av[mi][ni], 0, 0, 0);
            }
        __builtin_amdgcn_s_setprio(0);
        asm volatile("s_waitcnt vmcnt(0)" ::: "memory");
        __syncthreads();
        cur ^= 1;
    }

    const int mbase = m0 + wr * 64 + l4 * 4;
    const int nbase = n0 + wc * 32 + l15;
#pragma unroll
    for (int ni = 0; ni < 2; ++ni) {
        const int n = nbase + ni * 16;
        const float bq_ = bq[n];
        const float bv_ = bv[n];
#pragma unroll
        for (int mi = 0; mi < 4; ++mi) {
            const int mrow = mbase + mi * 16;
#pragma unroll
            for (int r = 0; r < 4; ++r) {
                qkb[(size_t)(mrow + r) * 1024 + n] = f2bf(aq[mi][ni][r] + bq_);
                vb [(size_t)(mrow + r) * 1024 + n] = f2bf(av[mi][ni][r] + bv_);
            }
        }
    }
}

// ---------------- tile decode for repack kernel ----------------
__device__ __forceinline__ void tile_decode(int tt, int& h, int& cls, int& jt, int& LK) {
    if (tt < 64)       { h = 0; cls = 0;               jt = tt;              LK = 2048; }
    else if (tt < 130) { h = 1; cls = (tt - 64) / 22;  jt = (tt - 64) % 22;  LK = (cls < 2) ? 683 : 682; }
    else if (tt < 200) { h = 2; cls = (tt - 130) / 10; jt = (tt - 130) % 10; LK = (cls < 4) ? 293 : 292; }
    else               { h = 3; cls = (tt - 200) / 5;  jt = (tt - 200) % 5;  LK = (cls < 7) ? 158 : 157; }
}

// ---------------- repack K and V into fragment-major class-tile layouts (merged) ---------
__global__ __launch_bounds__(256)
void repack_kv(const u16* __restrict__ qkb, const u16* __restrict__ vb,
               u16* __restrict__ kpack, u16* __restrict__ vpack) {
    __shared__ __align__(16) unsigned char sm[32768];   // K 16KB | V 16KB
    const int bid = blockIdx.x;
    const int b = bid & 1;
    const int tt = bid >> 1;
    int h, cls, jt, LK;
    tile_decode(tt, h, cls, jt, LK);
    const int s = (h == 0) ? 1 : (h == 1) ? 3 : (h == 2) ? 7 : 13;
    const int j0 = jt * 32;
    int nval = LK - j0; if (nval > 32) nval = 32;
    const int t = threadIdx.x;

#pragma unroll
    for (int i2 = 0; i2 < 4; ++i2) {
        const int p = i2 * 4096 + t * 16;
        const int j = p >> 9;
        const int cb = (p & 511) ^ ((j & 31) << 4);
        const int jj = (j < nval) ? j : (nval - 1);
        const size_t gofs = (size_t)((b * 2048 + cls + (j0 + jj) * s) * 1024 + h * 256) + (cb >> 1);
        g2l16(qkb + gofs, sm + p);
        g2l16(vb  + gofs, sm + 16384 + p);
    }
    asm volatile("s_waitcnt vmcnt(0)" ::: "memory");
    __syncthreads();
    if (nval < 32) {
        const int pb = 16384 + nval * 512;
        for (int off = pb + t * 16; off < 32768; off += 4096) {
            uint4 z; z.x = 0; z.y = 0; z.z = 0; z.w = 0;
            *(uint4*)(sm + off) = z;
        }
        __syncthreads();
    }
    const size_t tb = (size_t)(b * 265 + tt) * 8192;
    // kpack: 8 consecutive elems = same j, d0..d0+7
#pragma unroll
    for (int i2 = 0; i2 < 4; ++i2) {
        const int o = (i2 * 256 + t) * 8;
        const int dc = o >> 9;
        const int idx = (o >> 3) & 63;
        const int j = idx & 31;
        const int d0 = dc * 16 + (idx >> 5) * 8;
        const uint4 pk = *(const uint4*)(sm + j * 512 + ((d0 * 2) ^ ((j & 31) << 4)));
        *(uint4*)(kpack + tb + o) = pk;
    }
    // vpack: transposed gather from LDS
#pragma unroll
    for (int i2 = 0; i2 < 4; ++i2) {
        const int o = (i2 * 256 + t) * 8;
        const int slot2 = o >> 9;
        const int idx = (o >> 3) & 63;
        const int jb = (slot2 >> 3) * 16 + (idx >> 5) * 8;
        const int d = (slot2 & 7) * 32 + (idx & 31);
        u32 wpk[4];
#pragma unroll
        for (int e2 = 0; e2 < 4; ++e2) {
            const int j1 = jb + e2 * 2, j2 = j1 + 1;
            const u16 a0 = *(const u16*)(sm + 16384 + j1 * 512 + (((d >> 3) ^ (j1 & 31)) << 4) + (d & 7) * 2);
            const u16 a1 = *(const u16*)(sm + 16384 + j2 * 512 + (((d >> 3) ^ (j2 & 31)) << 4) + (d & 7) * 2);
            wpk[e2] = (u32)a0 | ((u32)a1 << 16);
        }
        uint4 pk; pk.x = wpk[0]; pk.y = wpk[1]; pk.z = wpk[2]; pk.w = wpk[3];
        *(uint4*)(vpack + tb + o) = pk;
    }
}

// ---------------- compressed flash attention: XCD-pinned, LDS double-buffered ----------
// Rebalanced per-XCD partition (per batch b = xcd&1, quad = xcd>>1):
//   quad0: h0 chunks 0..36 (37 slots, ~2MB)       quad1: h0 chunks 37..71 + h3 chunks 0..7 (43)
//   quad2: h1 (42 slots, 2.1MB)                    quad3: h2 + h3 chunks 8..25 (53, ~3.6MB)
__global__ __launch_bounds__(256, 2)
void attn_kernel(const u16* __restrict__ kpack, const u16* __restrict__ vpack,
                 u16* __restrict__ attnb, u16* __restrict__ partLo, u16* __restrict__ partHi,
                 float* __restrict__ mlbuf) {
    __shared__ __align__(16) unsigned char sm[65536];
    static constexpr int CGc[24] = {0,16,22,28,34,37,40,43,46,49,52,55,
                                    57,59,61,63,65,67,69,71,73,75,77,79};
    static constexpr int EXc[24] = {0,56,64,72,80,82,84,86,88,90,92,94,
                                    94,94,94,94,94,94,94,94,94,94,94,94};
    static constexpr int Tpc[24] = {72,14,14,14,5,5,5,5,5,5,5,2,2,2,2,2,2,2,2,2,2,2,2,2};

    const int bid = blockIdx.x;
    const int xcd = bid & 7, slot = bid >> 3;
    const int b = xcd & 1, quad = xcd >> 1;
    int hsel, hcb;
    if (quad == 0) {
        if (slot >= 37) return;
        hsel = 0; hcb = slot;
    } else if (quad == 1) {
        if (slot < 35)      { hsel = 0; hcb = 37 + slot; }
        else if (slot < 43) { hsel = 3; hcb = slot - 35; }
        else return;
    } else if (quad == 2) {
        if (slot >= 42) return;
        hsel = 1; hcb = slot;
    } else {
        if (slot < 35)      { hsel = 2; hcb = slot; }
        else if (slot < 53) { hsel = 3; hcb = 8 + (slot - 35); }
        else return;
    }
    int p = (hsel == 0) ? 0 : (hsel == 1) ? 1 : (hsel == 2) ? 4 : 11;
    int rb = hcb;
    while (rb >= Tpc[p]) { rb -= Tpc[p]; ++p; }
    int colg = CGc[p], exb = EXc[p];

    const int LQ = T_LQ[p];
    const int cB = T_cB[p], cA = T_cA[p], dA = T_dA[p];
    const int LKB = T_LkB[p], LKA = T_LkA[p];
    const int ktB = T_ktB[p], ktA = T_ktA[p];
    const int h = T_h[p], g = T_g[p], nc = T_nc[p], qt0 = T_qt[p];
    const int s = (h == 0) ? 1 : (h == 1) ? 3 : (h == 2) ? 7 : 13;

    int col = 0, chunk = 0, ntB = 0, tA0 = 0, nt = 0;
    for (int c = nc - 1; c >= 0; --c) {
        const int Mc = c << 7;
        int mmax = Mc + 128; if (mmax > LQ) mmax = LQ; mmax -= 1;
        int jB = mmax + cB; if (jB < 0) jB = 0; if (jB > LKB) jB = LKB;
        const int nb = (jB + 31) >> 5;
        int jlo = Mc + cA; if (jlo < 0) jlo = 0;
        int jhi = mmax + dA; if (jhi > LKA) jhi = LKA;
        const int ta = jlo >> 5;
        const int na = (jhi > jlo) ? (((jhi + 31) >> 5) - ta) : 0;
        const int n = nb + na;
        const int nch2 = (n + 7) >> 3;
        if (rb < nch2) { col = c; chunk = rb; ntB = nb; tA0 = ta; nt = n; break; }
        rb -= nch2; ++colg; exb += nch2 - 1;
    }
    const int nch = (nt + 7) >> 3;
    const int PBi = b * 265;

    const int t = threadIdx.x;
    const int w = t >> 6;
    const int l = t & 63;
    const int l31 = l & 31, h5 = l >> 5;
    const int m = (col << 7) + (w << 5) + l31;     // compressed query index
    const float c2 = 0.09016844f;                  // (1/16) * log2(e)
    const int lane16 = l * 16;                     // byte offset in packed tile

    // Q fragments from kpack class-g list tile (coalesced)
    bf16x8 qf[16];
    {
        const u16* qb = kpack + (size_t)(PBi + qt0 + col * 4 + w) * 8192 + l * 8;
#pragma unroll
        for (int dc = 0; dc < 16; ++dc)
            qf[dc] = *(const bf16x8*)(qb + dc * 512);
    }

    auto tileof = [&](int tv) -> int {
        return (tv < ntB) ? (ktB + tv) : (ktA + tA0 + (tv - ntB));
    };
    auto stage = [&](int tv, int buf) {
        const size_t tb = (size_t)(PBi + tileof(tv)) * 8192;
        unsigned char* Kd = sm + buf * 32768;
        unsigned char* Vd = Kd + 16384;
#pragma unroll
        for (int i2 = 0; i2 < 4; ++i2) {
            const int off = i2 * 4096 + t * 16;
            g2l16(kpack + tb + (off >> 1), Kd + off);
            g2l16(vpack + tb + (off >> 1), Vd + off);
        }
    };

    const int tt0 = chunk * 8;
    int tt1 = tt0 + 8; if (tt1 > nt) tt1 = nt;

    f32x16 o[8] = {};
    float mrun = -3.0e38f, lrun = 0.0f;

    stage(tt0, 0);
    asm volatile("s_waitcnt vmcnt(0)" ::: "memory");
    __syncthreads();

    int buf = 0;
    for (int tv = tt0; tv < tt1; ++tv) {
        if (tv + 1 < tt1) stage(tv + 1, buf ^ 1);

        int j0, lo, hi;
        if (tv < ntB) { j0 = tv << 5; lo = -100000; hi = cB; }
        else { const int ta = tA0 + tv - ntB; j0 = ta << 5; lo = cA; hi = dA; }

        const unsigned char* Kb = sm + buf * 32768;
        const unsigned char* Vb = Kb + 16384;

        // S^T = K * Q^T
        f32x16 sacc = {};
        __builtin_amdgcn_s_setprio(1);
#pragma unroll
        for (int dc = 0; dc < 16; ++dc) {
            const bf16x8 kf = *(const bf16x8*)(Kb + dc * 1024 + lane16);
            sacc = __builtin_amdgcn_mfma_f32_32x32x16_bf16(kf, qf[dc], sacc, 0, 0, 0);
        }
        __builtin_amdgcn_s_setprio(0);

        // mask + online softmax, in place (lane-local; e = j - m)
        const int ebase = j0 - m;
        float tmax = -3.0e38f;
#pragma unroll
        for (int r = 0; r < 16; ++r) {
            const int km = (r & 3) + 8 * (r >> 2) + 4 * h5;
            const int e = ebase + km;
            const bool ok = (e >= lo) && (e < hi);
            sacc[r] = ok ? sacc[r] : -3.0e38f;
            tmax = fmaxf(tmax, sacc[r]);
        }
        tmax = fmaxf(tmax, __shfl_xor(tmax, 32, 64));
        if (!__all(tmax <= mrun + 8.0f)) {     // defer-max
            const float mnew = fmaxf(mrun, tmax);
            const float fsc = __builtin_amdgcn_exp2f((mrun - mnew) * c2);
            lrun *= fsc;
#pragma unroll
            for (int ch = 0; ch < 8; ++ch)
#pragma unroll
                for (int r = 0; r < 16; ++r)
                    o[ch][r] *= fsc;
            mrun = mnew;
        }
        float psum = 0.0f;
#pragma unroll
        for (int r = 0; r < 16; ++r) {
            const float pv = (sacc[r] > -1.0e37f) ? __builtin_amdgcn_exp2f((sacc[r] - mrun) * c2) : 0.0f;
            sacc[r] = pv;
            psum += pv;
        }
        lrun += psum;

        // P -> bf16 fragments: cvt_pk + permlane32_swap
        uint32_t w0, w1, w2, w3, w4, w5, w6, w7;
        asm("v_cvt_pk_bf16_f32 %0,%1,%2" : "=v"(w0) : "v"(sacc[0]),  "v"(sacc[1]));
        asm("v_cvt_pk_bf16_f32 %0,%1,%2" : "=v"(w1) : "v"(sacc[2]),  "v"(sacc[3]));
        asm("v_cvt_pk_bf16_f32 %0,%1,%2" : "=v"(w2) : "v"(sacc[4]),  "v"(sacc[5]));
        asm("v_cvt_pk_bf16_f32 %0,%1,%2" : "=v"(w3) : "v"(sacc[6]),  "v"(sacc[7]));
        asm("v_cvt_pk_bf16_f32 %0,%1,%2" : "=v"(w4) : "v"(sacc[8]),  "v"(sacc[9]));
        asm("v_cvt_pk_bf16_f32 %0,%1,%2" : "=v"(w5) : "v"(sacc[10]), "v"(sacc[11]));
        asm("v_cvt_pk_bf16_f32 %0,%1,%2" : "=v"(w6) : "v"(sacc[12]), "v"(sacc[13]));
        asm("v_cvt_pk_bf16_f32 %0,%1,%2" : "=v"(w7) : "v"(sacc[14]), "v"(sacc[15]));
        asm("v_permlane32_swap_b32 %0, %1" : "+v"(w0), "+v"(w2));
        asm("v_permlane32_swap_b32 %0, %1" : "+v"(w1), "+v"(w3));
        asm("v_permlane32_swap_b32 %0, %1" : "+v"(w4), "+v"(w6));
        asm("v_permlane32_swap_b32 %0, %1" : "+v"(w5), "+v"(w7));
        union { uint32_t u[4]; bf16x8 v; } p0u, p1u;
        p0u.u[0] = w0; p0u.u[1] = w1; p0u.u[2] = w2; p0u.u[3] = w3;
        p1u.u[0] = w4; p1u.u[1] = w5; p1u.u[2] = w6; p1u.u[3] = w7;

        // O^T += V^T * P^T
        __builtin_amdgcn_s_setprio(1);
#pragma unroll
        for (int kk = 0; kk < 2; ++kk) {
            const bf16x8 pf = kk ? p1u.v : p0u.v;
#pragma unroll
            for (int ch = 0; ch < 8; ++ch) {
                const bf16x8 vf = *(const bf16x8*)(Vb + (kk * 8 + ch) * 1024 + lane16);
                o[ch] = __builtin_amdgcn_mfma_f32_32x32x16_bf16(vf, pf, o[ch], 0, 0, 0);
            }
        }
        __builtin_amdgcn_s_setprio(0);

        asm volatile("s_waitcnt vmcnt(0)" ::: "memory");
        __syncthreads();
        buf ^= 1;
    }

    lrun += __shfl_xor(lrun, 32, 64);

    float scale = 1.0f;
    u16* ab;
    const int qm = (w << 5) + l31;
    if (nch == 1) {
        scale = (lrun > 0.0f) ? 1.0f / lrun : 0.0f;
        ab = attnb + ((size_t)(b * 2048 + g + m * s)) * 1024 + h * 256;
    } else {
        if (h5 == 0 && m < LQ) {
            const int colid = b * 81 + colg;
            mlbuf[(size_t)((colid * 8 + chunk) * 256) + qm * 2]     = mrun;
            mlbuf[(size_t)((colid * 8 + chunk) * 256) + qm * 2 + 1] = lrun;
        }
        if (chunk == 0)
            ab = attnb + ((size_t)(b * 2048 + g + m * s)) * 1024 + h * 256;
        else
            ab = partO_addr(partLo, partHi, b * 94 + exb + chunk - 1) + (size_t)qm * 256;
    }

    if (m < LQ) {
#pragma unroll
        for (int ch = 0; ch < 8; ++ch) {
#pragma unroll
            for (int g2 = 0; g2 < 4; ++g2) {
                ushort4 wv4;
                wv4.x = f2bf(o[ch][g2 * 4 + 0] * scale);
                wv4.y = f2bf(o[ch][g2 * 4 + 1] * scale);
                wv4.z = f2bf(o[ch][g2 * 4 + 2] * scale);
                wv4.w = f2bf(o[ch][g2 * 4 + 3] * scale);
                *(ushort4*)(ab + ch * 32 + 8 * g2 + 4 * h5) = wv4;
            }
        }
    }
}

// ---------------- combine chunked columns ----------------
__global__ __launch_bounds__(256)
void combine_kernel(const u16* __restrict__ partLo, const u16* __restrict__ partHi,
                    const float* __restrict__ mlbuf, u16* __restrict__ attnb) {
    static constexpr int MCc[24] = {0,14,18,22,26,28,30,32,34,36,38,40,
                                    40,40,40,40,40,40,40,40,40,40,40,40};
    static constexpr int CGc[24] = {0,16,22,28,34,37,40,43,46,49,52,55,
                                    57,59,61,63,65,67,69,71,73,75,77,79};
    static constexpr int EXc[24] = {0,56,64,72,80,82,84,86,88,90,92,94,
                                    94,94,94,94,94,94,94,94,94,94,94,94};
    const int b = blockIdx.x & 1;
    int rb = blockIdx.x >> 1;
    int p = 0, base = 0, colg = 0, exb = 0;
#pragma unroll
    for (int i = 1; i < 24; ++i)
        if (rb >= MCc[i]) { p = i; base = MCc[i]; colg = CGc[i]; exb = EXc[i]; }
    rb -= base;

    int col = 0, nch = 0;
    for (int c = T_nc[p] - 1; c >= 0; --c) {
        int nb, ta, n;
        col_geom(p, c, nb, ta, n);
        const int nc2 = (n + 7) >> 3;
        if (nc2 > 1) {
            if (rb == 0) { col = c; nch = nc2; break; }
            --rb;
        }
        ++colg; exb += nc2 - 1;
    }
    const int h = T_h[p], g = T_g[p];
    const int s = (h == 0) ? 1 : (h == 1) ? 3 : (h == 2) ? 7 : 13;
    const int LQ = T_LQ[p];
    const int colid = b * 81 + colg;
    const float c2 = 0.09016844f;

    const int t = threadIdx.x;
    const int q = t >> 1, dpart = (t & 1) * 128;
    const int m = (col << 7) + q;

    float mj[8], lj[8];
#pragma unroll
    for (int j5 = 0; j5 < 8; ++j5) {
        if (j5 < nch) {
            mj[j5] = mlbuf[(size_t)((colid * 8 + j5) * 256) + q * 2];
            lj[j5] = mlbuf[(size_t)((colid * 8 + j5) * 256) + q * 2 + 1];
        } else { mj[j5] = -3.0e38f; lj[j5] = 0.0f; }
    }
    float M = -3.0e38f;
#pragma unroll
    for (int j5 = 0; j5 < 8; ++j5) if (j5 < nch) M = fmaxf(M, mj[j5]);
    float L = 0.0f, al[8];
#pragma unroll
    for (int j5 = 0; j5 < 8; ++j5) {
        al[j5] = (j5 < nch) ? __builtin_amdgcn_exp2f((mj[j5] - M) * c2) : 0.0f;
        L += lj[j5] * al[j5];
    }
    const float inv = (L > 0.0f) ? 1.0f / L : 0.0f;
#pragma unroll
    for (int j5 = 0; j5 < 8; ++j5) al[j5] *= inv;

    u16* dst = attnb + ((size_t)(b * 2048 + g + m * s)) * 1024 + h * 256 + dpart;

    for (int ss = 0; ss < 4; ++ss) {
        float acc32[32];
#pragma unroll
        for (int e = 0; e < 32; ++e) acc32[e] = 0.0f;
#pragma unroll
        for (int j5 = 0; j5 < 8; ++j5) {
            if (j5 >= nch) continue;
            const u16* src = (j5 == 0)
                ? (dst + ss * 32)
                : (partO_addr_c(partLo, partHi, b * 94 + exb + j5 - 1) + (size_t)q * 256 + dpart + ss * 32);
            const float sc = al[j5];
#pragma unroll
            for (int w4 = 0; w4 < 4; ++w4) {
                const uint4 pk = *(const uint4*)(src + w4 * 8);
                const u32 ww[4] = { pk.x, pk.y, pk.z, pk.w };
#pragma unroll
                for (int e = 0; e < 4; ++e) {
                    union { u32 u; float f; } lo2, hi2;
                    lo2.u = ww[e] << 16;
                    hi2.u = ww[e] & 0xffff0000u;
                    acc32[w4 * 8 + e * 2]     += sc * lo2.f;
                    acc32[w4 * 8 + e * 2 + 1] += sc * hi2.f;
                }
            }
        }
        if (m < LQ) {
#pragma unroll
            for (int w4 = 0; w4 < 4; ++w4) {
                uint4 pk;
                pk.x = (u32)f2bf(acc32[w4 * 8 + 0]) | ((u32)f2bf(acc32[w4 * 8 + 1]) << 16);
                pk.y = (u32)f2bf(acc32[w4 * 8 + 2]) | ((u32)f2bf(acc32[w4 * 8 + 3]) << 16);
                pk.z = (u32)f2bf(acc32[w4 * 8 + 4]) | ((u32)f2bf(acc32[w4 * 8 + 5]) << 16);
                pk.w = (u32)f2bf(acc32[w4 * 8 + 6]) | ((u32)f2bf(acc32[w4 * 8 + 7]) << 16);
                *(uint4*)(dst + ss * 32 + w4 * 8) = pk;
            }
        }
    }
}

// ---------------- output GEMM: out = attnb @ Wo^T + bo (f32) ----------------
__global__ __launch_bounds__(256, 3)
void gemm_out(const u16* __restrict__ A, const u16* __restrict__ Bw,
              const float* __restrict__ bias, float* __restrict__ outp) {
    __shared__ __align__(16) u16 As[2][4096], Bs[2][2048];
    const int bid = blockIdx.x;
    const int xcd = bid & 7, slot = bid >> 3;
    const int m0 = (xcd * 4 + (slot & 3)) * 128;
    const int n0 = (slot >> 2) * 64;
    const int t = threadIdx.x;
    const int lane = t & 63;
    const int wid = t >> 6;
    const int wr = wid >> 1, wc = wid & 1;
    const int l15 = lane & 15, l4 = lane >> 4;

    f32x4 acc[4][2] = {};

    auto stage = [&](int buf, int kt) {
        const int kbase = kt * 32;
#pragma unroll
        for (int c2 = 0; c2 < 2; ++c2) {
            const int pp = c2 * 4096 + t * 16;
            g2l16(A + (size_t)(m0 + (pp >> 6)) * 1024 + kbase + ((pp & 63) >> 1), (char*)As[buf] + pp);
        }
        const int pb = t * 16;
        g2l16(Bw + (size_t)(n0 + (pb >> 6)) * 1024 + kbase + ((pb & 63) >> 1), (char*)Bs[buf] + pb);
    };

    stage(0, 0);
    asm volatile("s_waitcnt vmcnt(0)" ::: "memory");
    __syncthreads();

    int cur = 0;
    for (int kt = 0; kt < 32; ++kt) {
        if (kt + 1 < 32) stage(cur ^ 1, kt + 1);
        bf16x8 af[4], bfr[2];
#pragma unroll
        for (int mi = 0; mi < 4; ++mi)
            af[mi] = *(const bf16x8*)((const char*)As[cur] + (wr * 64 + mi * 16 + l15) * 64 + l4 * 16);
#pragma unroll
        for (int ni = 0; ni < 2; ++ni)
            bfr[ni] = *(const bf16x8*)((const char*)Bs[cur] + (wc * 32 + ni * 16 + l15) * 64 + l4 * 16);
        __builtin_amdgcn_s_setprio(1);
#pragma unroll
        for (int mi = 0; mi < 4; ++mi)
#pragma unroll
            for (int ni = 0; ni < 2; ++ni)
                acc[mi][ni] = __builtin_amdgcn_mfma_f32_16x16x32_bf16(af[mi], bfr[ni], acc[mi][ni], 0, 0, 0);
        __builtin_amdgcn_s_setprio(0);
        asm volatile("s_waitcnt vmcnt(0)" ::: "memory");
        __syncthreads();
        cur ^= 1;
    }

    const int mbase = m0 + wr * 64 + l4 * 4;
    const int nbase = n0 + wc * 32 + l15;
#pragma unroll
    for (int ni = 0; ni < 2; ++ni) {
        const int n = nbase + ni * 16;
        const float bv = bias[n];
#pragma unroll
        for (int mi = 0; mi < 4; ++mi) {
            const int mrow = mbase + mi * 16;
#pragma unroll
            for (int r = 0; r < 4; ++r)
                outp[(size_t)(mrow + r) * 1024 + n] = acc[mi][ni][r] + bv;
        }
    }
}

extern "C" void kernel_launch(void* const* d_in, const int* in_sizes, int n_in,
                              void* d_out, int out_size, void* d_ws, size_t ws_size,
                              hipStream_t stream) {
    const float* x   = (const float*)d_in[0];
    const float* Wqk = (const float*)d_in[1];
    const float* bqk = (const float*)d_in[2];
    const float* Wv  = (const float*)d_in[3];
    const float* bv  = (const float*)d_in[4];
    const float* Wo  = (const float*)d_in[5];
    const float* bo  = (const float*)d_in[6];
    float* out = (float*)d_out;

    u16* ws     = (u16*)d_ws;
    u16* xb     = ws;             // 4,194,304 (dead after gemm_qkv -> attnb overlay)
    u16* wqkb   = ws + 4194304;   // 1,048,576 (dead after gemm_qkv -> partHi overlay)
    u16* wvb    = ws + 5242880;   // 1,048,576 (dead after gemm_qkv)
    u16* wob    = ws + 6291456;   // 1,048,576 (live until gemm_out)
    u16* qkb    = ws + 7340032;   // 4,194,304 (dead after repack_kv -> partLo overlay)
    u16* vb     = ws + 11534336;  // 4,194,304 (dead after repack_kv)
    u16* kpack  = ws + 15728640;  // 4,341,760
    u16* vpack  = ws + 20070400;  // 4,341,760 (ends 24,412,160 u16 = 48.8 MB)
    u16* attnb  = ws;             // overlays xb
    u16* partLo = ws + 7340032;   // 128 slots x 32768 u16 (overlays qkb)
    u16* partHi = ws + 4194304;   // 60 slots (overlays wqkb+wvb)
    float* mlbuf = (float*)d_out; // d_out dead until gemm_out

    cvt_kernel<<<7168, 256, 0, stream>>>(x, Wqk, Wv, Wo, ws);
    gemm_qkv<<<512, 256, 0, stream>>>(xb, wqkb, wvb, bqk, bv, qkb, vb);
    repack_kv<<<530, 256, 0, stream>>>(qkb, vb, kpack, vpack);
    attn_kernel<<<424, 256, 0, stream>>>(kpack, vpack, attnb, partLo, partHi, mlbuf);
    combine_kernel<<<80, 256, 0, stream>>>(partLo, partHi, mlbuf, attnb);
    gemm_out<<<512, 256, 0, stream>>>(attnb, wob, bo, out);
}

// Round 13
// 112.267 us; speedup vs baseline: 1.1722x; 1.0805x over previous
//
#include <hip/hip_runtime.h>
#include <cstdint>
#include <cstddef>

typedef unsigned short u16;
typedef uint32_t u32;
typedef __bf16 bf16x8 __attribute__((ext_vector_type(8)));
typedef float f32x4 __attribute__((ext_vector_type(4)));
typedef float f32x16 __attribute__((ext_vector_type(16)));

typedef __attribute__((address_space(1))) void gvoid;
typedef __attribute__((address_space(3))) void lvoid;

__device__ __forceinline__ void g2l16(const void* g, void* l) {
    __builtin_amdgcn_global_load_lds((gvoid*)g, (lvoid*)l, 16, 0, 0);
}

__device__ __forceinline__ u16 f2bf(float f) {
    union { float f; uint32_t u; } v;
    v.f = f;
    uint32_t r = (v.u + 0x7FFFu + ((v.u >> 16) & 1u)) >> 16;
    return (u16)r;
}

// ================= compressed-class problem tables (per batch: 24 problems) ==============
__device__ const int T_h[24]  = {0, 1,1,1, 2,2,2,2,2,2,2, 3,3,3,3,3,3,3,3,3,3,3,3,3};
__device__ const int T_g[24]  = {0, 0,1,2, 0,1,2,3,4,5,6, 0,1,2,3,4,5,6,7,8,9,10,11,12};
__device__ const int T_qt[24] = {0, 64,86,108, 130,140,150,160,170,180,190,
                                 200,205,210,215,220,225,230,235,240,245,250,255,260};
__device__ const int T_LQ[24] = {2048, 683,683,682, 293,293,293,293,292,292,292,
                                 158,158,158,158,158,158,158,157,157,157,157,157,157};
__device__ const int T_ktB[24]= {0, 64,86,108, 140,150,160,170,180,190,130,
                                 245,250,255,260,200,205,210,215,220,225,230,235,240};
__device__ const int T_LkB[24]= {2048, 683,683,682, 293,293,293,292,292,292,293,
                                 157,157,157,157,158,158,158,158,158,158,158,157,157};
__device__ const int T_cB[24] = {1, -341,-341,-341, -146,-146,-146,-146,-146,-146,-145,
                                 -79,-79,-79,-79,-78,-78,-78,-78,-78,-78,-78,-78,-78};
__device__ const int T_ktA[24]= {0, 108,64,86, 180,190,130,140,150,160,170,
                                 215,220,225,230,235,240,245,250,255,260,200,205,210};
__device__ const int T_LkA[24]= {0, 682,683,683, 292,292,293,293,293,293,292,
                                 158,158,158,158,157,157,157,157,157,157,158,158,158};
__device__ const int T_cA[24] = {0, -342,-341,-341, -147,-147,-146,-146,-146,-146,-146,
                                 -79,-79,-79,-79,-79,-79,-79,-79,-79,-79,-78,-78,-78};
__device__ const int T_dA[24] = {0, 0,1,1, 0,0,1,1,1,1,1, 0,0,0,0,0,0,0,0,0,0,1,1,1};
__device__ const int T_nc[24] = {16, 6,6,6, 3,3,3,3,3,3,3, 2,2,2,2,2,2,2,2,2,2,2,2,2};

__device__ __forceinline__ void col_geom(int p, int c, int& ntB, int& tA0, int& nt) {
    const int LQ = T_LQ[p];
    const int Mc = c << 7;
    int mmax = Mc + 128; if (mmax > LQ) mmax = LQ; mmax -= 1;
    int jB = mmax + T_cB[p];
    if (jB < 0) jB = 0;
    if (jB > T_LkB[p]) jB = T_LkB[p];
    ntB = (jB + 31) >> 5;
    int jlo = Mc + T_cA[p]; if (jlo < 0) jlo = 0;
    int jhi = mmax + T_dA[p];
    if (jhi > T_LkA[p]) jhi = T_LkA[p];
    tA0 = jlo >> 5;
    int ntA = 0;
    if (jhi > jlo) ntA = ((jhi + 31) >> 5) - tA0;
    nt = ntB + ntA;
}

__device__ __forceinline__ u16* partO_addr(u16* lo, u16* hi, int slot) {
    return (slot < 128) ? (lo + (size_t)slot * 32768) : (hi + (size_t)(slot - 128) * 32768);
}
__device__ __forceinline__ const u16* partO_addr_c(const u16* lo, const u16* hi, int slot) {
    return (slot < 128) ? (lo + (size_t)slot * 32768) : (hi + (size_t)(slot - 128) * 32768);
}

// ---------------- fp32 -> bf16 conversion of x, Wqk, Wv, Wo into ws ----------------
__global__ __launch_bounds__(256)
void cvt_kernel(const float* __restrict__ x, const float* __restrict__ wqk,
                const float* __restrict__ wv, const float* __restrict__ wo,
                u16* __restrict__ out) {
    int i = (blockIdx.x * 256 + threadIdx.x) * 4;
    const float* src;
    int off;
    if (i < 4194304)      { src = x;   off = 0; }
    else if (i < 5242880) { src = wqk; off = 4194304; }
    else if (i < 6291456) { src = wv;  off = 5242880; }
    else                  { src = wo;  off = 6291456; }
    float4 v = *(const float4*)(src + (i - off));
    ushort4 o;
    o.x = f2bf(v.x); o.y = f2bf(v.y); o.z = f2bf(v.z); o.w = f2bf(v.w);
    *(ushort4*)(out + i) = o;
}

// ---------------- fused QK+V projection GEMM, row-major bf16 outputs ----------------
// BK=64, XOR-swizzled staging (chunk ^= row&7 within 128B rows) -> conflict-free ds_read_b128.
// 2-D XCD map: xcd = (m-group 0..3) x (n-half 0..1).
__global__ __launch_bounds__(256, 2)
void gemm_qkv(const u16* __restrict__ A, const u16* __restrict__ Bq, const u16* __restrict__ Bv,
              const float* __restrict__ bq, const float* __restrict__ bv,
              u16* __restrict__ qkb, u16* __restrict__ vb) {
    __shared__ __align__(16) u16 As[2][8192], Bqs[2][4096], Bvs[2][4096];
    const int bid = blockIdx.x;
    const int xcd = bid & 7, slot = bid >> 3;
    const int m0 = ((xcd >> 1) * 8 + (slot & 7)) * 128;
    const int n0 = ((xcd & 1) * 8 + (slot >> 3)) * 64;
    const int t = threadIdx.x;
    const int lane = t & 63;
    const int wid = t >> 6;
    const int wr = wid >> 1, wc = wid & 1;
    const int l15 = lane & 15, l4 = lane >> 4;

    f32x4 aq[4][2] = {}, av[4][2] = {};

    auto stage = [&](int buf, int kt) {
        const int kbase = kt * 64;
#pragma unroll
        for (int c2 = 0; c2 < 4; ++c2) {
            const int p = c2 * 4096 + t * 16;
            const int row = p >> 7;
            const int cs = ((p >> 4) & 7) ^ (row & 7);
            g2l16(A + (size_t)(m0 + row) * 1024 + kbase + cs * 8, (char*)As[buf] + p);
        }
#pragma unroll
        for (int c2 = 0; c2 < 2; ++c2) {
            const int p = c2 * 4096 + t * 16;
            const int row = p >> 7;
            const int cs = ((p >> 4) & 7) ^ (row & 7);
            const size_t so = (size_t)(n0 + row) * 1024 + kbase + cs * 8;
            g2l16(Bq + so, (char*)Bqs[buf] + p);
            g2l16(Bv + so, (char*)Bvs[buf] + p);
        }
    };

    stage(0, 0);
    asm volatile("s_waitcnt vmcnt(0)" ::: "memory");
    __syncthreads();

    int cur = 0;
    for (int kt = 0; kt < 16; ++kt) {
        if (kt + 1 < 16) stage(cur ^ 1, kt + 1);
#pragma unroll
        for (int kk = 0; kk < 2; ++kk) {
            bf16x8 af[4], bfq[2], bfv[2];
#pragma unroll
            for (int mi = 0; mi < 4; ++mi) {
                const int row = wr * 64 + mi * 16 + l15;
                af[mi] = *(const bf16x8*)((const char*)As[cur] + row * 128 + (((kk * 4 + l4) ^ (row & 7)) << 4));
            }
#pragma unroll
            for (int ni = 0; ni < 2; ++ni) {
                const int row = wc * 32 + ni * 16 + l15;
                const int co = row * 128 + (((kk * 4 + l4) ^ (row & 7)) << 4);
                bfq[ni] = *(const bf16x8*)((const char*)Bqs[cur] + co);
                bfv[ni] = *(const bf16x8*)((const char*)Bvs[cur] + co);
            }
            __builtin_amdgcn_s_setprio(1);
#pragma unroll
            for (int mi = 0; mi < 4; ++mi)
#pragma unroll
                for (int ni = 0; ni < 2; ++ni) {
                    aq[mi][ni] = __builtin_amdgcn_mfma_f32_16x16x32_bf16(af[mi], bfq[ni], aq[mi][ni], 0, 0, 0);
                    av[mi][ni] = __builtin_amdgcn_mfma_f32_16x16x32_bf16(af[mi], bfv[ni], av[mi][ni], 0, 0, 0);
                }
            __builtin_amdgcn_s_setprio(0);
        }
        asm volatile("s_waitcnt vmcnt(0)" ::: "memory");
        __syncthreads();
        cur ^= 1;
    }

    const int mbase = m0 + wr * 64 + l4 * 4;
    const int nbase = n0 + wc * 32 + l15;
#pragma unroll
    for (int ni = 0; ni < 2; ++ni) {
        const int n = nbase + ni * 16;
        const float bq_ = bq[n];
        const float bv_ = bv[n];
#pragma unroll
        for (int mi = 0; mi < 4; ++mi) {
            const int mrow = mbase + mi * 16;
#pragma unroll
            for (int r = 0; r < 4; ++r) {
                qkb[(size_t)(mrow + r) * 1024 + n] = f2bf(aq[mi][ni][r] + bq_);
                vb [(size_t)(mrow + r) * 1024 + n] = f2bf(av[mi][ni][r] + bv_);
            }
        }
    }
}

// ---------------- tile decode for repack kernel ----------------
__device__ __forceinline__ void tile_decode(int tt, int& h, int& cls, int& jt, int& LK) {
    if (tt < 64)       { h = 0; cls = 0;               jt = tt;              LK = 2048; }
    else if (tt < 130) { h = 1; cls = (tt - 64) / 22;  jt = (tt - 64) % 22;  LK = (cls < 2) ? 683 : 682; }
    else if (tt < 200) { h = 2; cls = (tt - 130) / 10; jt = (tt - 130) % 10; LK = (cls < 4) ? 293 : 292; }
    else               { h = 3; cls = (tt - 200) / 5;  jt = (tt - 200) % 5;  LK = (cls < 7) ? 158 : 157; }
}

// ---------------- repack K and V into fragment-major class-tile layouts (merged) ---------
__global__ __launch_bounds__(256)
void repack_kv(const u16* __restrict__ qkb, const u16* __restrict__ vb,
               u16* __restrict__ kpack, u16* __restrict__ vpack) {
    __shared__ __align__(16) unsigned char sm[32768];   // K 16KB | V 16KB
    const int bid = blockIdx.x;
    const int b = bid & 1;
    const int tt = bid >> 1;
    int h, cls, jt, LK;
    tile_decode(tt, h, cls, jt, LK);
    const int s = (h == 0) ? 1 : (h == 1) ? 3 : (h == 2) ? 7 : 13;
    const int j0 = jt * 32;
    int nval = LK - j0; if (nval > 32) nval = 32;
    const int t = threadIdx.x;

#pragma unroll
    for (int i2 = 0; i2 < 4; ++i2) {
        const int p = i2 * 4096 + t * 16;
        const int j = p >> 9;
        const int cb = (p & 511) ^ ((j & 31) << 4);
        const int jj = (j < nval) ? j : (nval - 1);
        const size_t gofs = (size_t)((b * 2048 + cls + (j0 + jj) * s) * 1024 + h * 256) + (cb >> 1);
        g2l16(qkb + gofs, sm + p);
        g2l16(vb  + gofs, sm + 16384 + p);
    }
    asm volatile("s_waitcnt vmcnt(0)" ::: "memory");
    __syncthreads();
    if (nval < 32) {
        const int pb = 16384 + nval * 512;
        for (int off = pb + t * 16; off < 32768; off += 4096) {
            uint4 z; z.x = 0; z.y = 0; z.z = 0; z.w = 0;
            *(uint4*)(sm + off) = z;
        }
        __syncthreads();
    }
    const size_t tb = (size_t)(b * 265 + tt) * 8192;
    // kpack: 8 consecutive elems = same j, d0..d0+7
#pragma unroll
    for (int i2 = 0; i2 < 4; ++i2) {
        const int o = (i2 * 256 + t) * 8;
        const int dc = o >> 9;
        const int idx = (o >> 3) & 63;
        const int j = idx & 31;
        const int d0 = dc * 16 + (idx >> 5) * 8;
        const uint4 pk = *(const uint4*)(sm + j * 512 + ((d0 * 2) ^ ((j & 31) << 4)));
        *(uint4*)(kpack + tb + o) = pk;
    }
    // vpack: transposed gather from LDS
#pragma unroll
    for (int i2 = 0; i2 < 4; ++i2) {
        const int o = (i2 * 256 + t) * 8;
        const int slot2 = o >> 9;
        const int idx = (o >> 3) & 63;
        const int jb = (slot2 >> 3) * 16 + (idx >> 5) * 8;
        const int d = (slot2 & 7) * 32 + (idx & 31);
        u32 wpk[4];
#pragma unroll
        for (int e2 = 0; e2 < 4; ++e2) {
            const int j1 = jb + e2 * 2, j2 = j1 + 1;
            const u16 a0 = *(const u16*)(sm + 16384 + j1 * 512 + (((d >> 3) ^ (j1 & 31)) << 4) + (d & 7) * 2);
            const u16 a1 = *(const u16*)(sm + 16384 + j2 * 512 + (((d >> 3) ^ (j2 & 31)) << 4) + (d & 7) * 2);
            wpk[e2] = (u32)a0 | ((u32)a1 << 16);
        }
        uint4 pk; pk.x = wpk[0]; pk.y = wpk[1]; pk.z = wpk[2]; pk.w = wpk[3];
        *(uint4*)(vpack + tb + o) = pk;
    }
}

// ---------------- compressed flash attention: XCD-pinned, LDS double-buffered ----------
__global__ __launch_bounds__(256, 2)
void attn_kernel(const u16* __restrict__ kpack, const u16* __restrict__ vpack,
                 u16* __restrict__ attnb, u16* __restrict__ partLo, u16* __restrict__ partHi,
                 float* __restrict__ mlbuf) {
    __shared__ __align__(16) unsigned char sm[65536];
    static constexpr int CGc[24] = {0,16,22,28,34,37,40,43,46,49,52,55,
                                    57,59,61,63,65,67,69,71,73,75,77,79};
    static constexpr int EXc[24] = {0,56,64,72,80,82,84,86,88,90,92,94,
                                    94,94,94,94,94,94,94,94,94,94,94,94};
    static constexpr int Tpc[24] = {72,14,14,14,5,5,5,5,5,5,5,2,2,2,2,2,2,2,2,2,2,2,2,2};

    const int bid = blockIdx.x;
    const int xcd = bid & 7, slot = bid >> 3;
    const int b = xcd & 1, quad = xcd >> 1;
    int hsel, hcb;
    if (quad == 0) {
        if (slot >= 37) return;
        hsel = 0; hcb = slot;
    } else if (quad == 1) {
        if (slot < 35)      { hsel = 0; hcb = 37 + slot; }
        else if (slot < 43) { hsel = 3; hcb = slot - 35; }
        else return;
    } else if (quad == 2) {
        if (slot >= 42) return;
        hsel = 1; hcb = slot;
    } else {
        if (slot < 35)      { hsel = 2; hcb = slot; }
        else if (slot < 53) { hsel = 3; hcb = 8 + (slot - 35); }
        else return;
    }
    int p = (hsel == 0) ? 0 : (hsel == 1) ? 1 : (hsel == 2) ? 4 : 11;
    int rb = hcb;
    while (rb >= Tpc[p]) { rb -= Tpc[p]; ++p; }
    int colg = CGc[p], exb = EXc[p];

    const int LQ = T_LQ[p];
    const int cB = T_cB[p], cA = T_cA[p], dA = T_dA[p];
    const int LKB = T_LkB[p], LKA = T_LkA[p];
    const int ktB = T_ktB[p], ktA = T_ktA[p];
    const int h = T_h[p], g = T_g[p], nc = T_nc[p], qt0 = T_qt[p];
    const int s = (h == 0) ? 1 : (h == 1) ? 3 : (h == 2) ? 7 : 13;

    int col = 0, chunk = 0, ntB = 0, tA0 = 0, nt = 0;
    for (int c = nc - 1; c >= 0; --c) {
        const int Mc = c << 7;
        int mmax = Mc + 128; if (mmax > LQ) mmax = LQ; mmax -= 1;
        int jB = mmax + cB; if (jB < 0) jB = 0; if (jB > LKB) jB = LKB;
        const int nb = (jB + 31) >> 5;
        int jlo = Mc + cA; if (jlo < 0) jlo = 0;
        int jhi = mmax + dA; if (jhi > LKA) jhi = LKA;
        const int ta = jlo >> 5;
        const int na = (jhi > jlo) ? (((jhi + 31) >> 5) - ta) : 0;
        const int n = nb + na;
        const int nch2 = (n + 7) >> 3;
        if (rb < nch2) { col = c; chunk = rb; ntB = nb; tA0 = ta; nt = n; break; }
        rb -= nch2; ++colg; exb += nch2 - 1;
    }
    const int nch = (nt + 7) >> 3;
    const int PBi = b * 265;

    const int t = threadIdx.x;
    const int w = t >> 6;
    const int l = t & 63;
    const int l31 = l & 31, h5 = l >> 5;
    const int m = (col << 7) + (w << 5) + l31;     // compressed query index
    const float c2 = 0.09016844f;                  // (1/16) * log2(e)
    const int lane16 = l * 16;                     // byte offset in packed tile

    // Q fragments from kpack class-g list tile (coalesced)
    bf16x8 qf[16];
    {
        const u16* qb = kpack + (size_t)(PBi + qt0 + col * 4 + w) * 8192 + l * 8;
#pragma unroll
        for (int dc = 0; dc < 16; ++dc)
            qf[dc] = *(const bf16x8*)(qb + dc * 512);
    }

    auto tileof = [&](int tv) -> int {
        return (tv < ntB) ? (ktB + tv) : (ktA + tA0 + (tv - ntB));
    };
    auto stage = [&](int tv, int buf) {
        const size_t tb = (size_t)(PBi + tileof(tv)) * 8192;
        unsigned char* Kd = sm + buf * 32768;
        unsigned char* Vd = Kd + 16384;
#pragma unroll
        for (int i2 = 0; i2 < 4; ++i2) {
            const int off = i2 * 4096 + t * 16;
            g2l16(kpack + tb + (off >> 1), Kd + off);
            g2l16(vpack + tb + (off >> 1), Vd + off);
        }
    };

    const int tt0 = chunk * 8;
    int tt1 = tt0 + 8; if (tt1 > nt) tt1 = nt;

    f32x16 o[8] = {};
    float mrun = -3.0e38f, lrun = 0.0f;

    stage(tt0, 0);
    asm volatile("s_waitcnt vmcnt(0)" ::: "memory");
    __syncthreads();

    int buf = 0;
    for (int tv = tt0; tv < tt1; ++tv) {
        if (tv + 1 < tt1) stage(tv + 1, buf ^ 1);

        int j0, lo, hi;
        if (tv < ntB) { j0 = tv << 5; lo = -100000; hi = cB; }
        else { const int ta = tA0 + tv - ntB; j0 = ta << 5; lo = cA; hi = dA; }

        const unsigned char* Kb = sm + buf * 32768;
        const unsigned char* Vb = Kb + 16384;

        // S^T = K * Q^T
        f32x16 sacc = {};
        __builtin_amdgcn_s_setprio(1);
#pragma unroll
        for (int dc = 0; dc < 16; ++dc) {
            const bf16x8 kf = *(const bf16x8*)(Kb + dc * 1024 + lane16);
            sacc = __builtin_amdgcn_mfma_f32_32x32x16_bf16(kf, qf[dc], sacc, 0, 0, 0);
        }
        __builtin_amdgcn_s_setprio(0);

        // mask + online softmax, in place (lane-local; e = j - m)
        const int ebase = j0 - m;
        float tmax = -3.0e38f;
#pragma unroll
        for (int r = 0; r < 16; ++r) {
            const int km = (r & 3) + 8 * (r >> 2) + 4 * h5;
            const int e = ebase + km;
            const bool ok = (e >= lo) && (e < hi);
            sacc[r] = ok ? sacc[r] : -3.0e38f;
            tmax = fmaxf(tmax, sacc[r]);
        }
        tmax = fmaxf(tmax, __shfl_xor(tmax, 32, 64));
        if (!__all(tmax <= mrun + 8.0f)) {     // defer-max
            const float mnew = fmaxf(mrun, tmax);
            const float fsc = __builtin_amdgcn_exp2f((mrun - mnew) * c2);
            lrun *= fsc;
#pragma unroll
            for (int ch = 0; ch < 8; ++ch)
#pragma unroll
                for (int r = 0; r < 16; ++r)
                    o[ch][r] *= fsc;
            mrun = mnew;
        }
        float psum = 0.0f;
#pragma unroll
        for (int r = 0; r < 16; ++r) {
            const float pv = (sacc[r] > -1.0e37f) ? __builtin_amdgcn_exp2f((sacc[r] - mrun) * c2) : 0.0f;
            sacc[r] = pv;
            psum += pv;
        }
        lrun += psum;

        // P -> bf16 fragments: cvt_pk + permlane32_swap
        uint32_t w0, w1, w2, w3, w4, w5, w6, w7;
        asm("v_cvt_pk_bf16_f32 %0,%1,%2" : "=v"(w0) : "v"(sacc[0]),  "v"(sacc[1]));
        asm("v_cvt_pk_bf16_f32 %0,%1,%2" : "=v"(w1) : "v"(sacc[2]),  "v"(sacc[3]));
        asm("v_cvt_pk_bf16_f32 %0,%1,%2" : "=v"(w2) : "v"(sacc[4]),  "v"(sacc[5]));
        asm("v_cvt_pk_bf16_f32 %0,%1,%2" : "=v"(w3) : "v"(sacc[6]),  "v"(sacc[7]));
        asm("v_cvt_pk_bf16_f32 %0,%1,%2" : "=v"(w4) : "v"(sacc[8]),  "v"(sacc[9]));
        asm("v_cvt_pk_bf16_f32 %0,%1,%2" : "=v"(w5) : "v"(sacc[10]), "v"(sacc[11]));
        asm("v_cvt_pk_bf16_f32 %0,%1,%2" : "=v"(w6) : "v"(sacc[12]), "v"(sacc[13]));
        asm("v_cvt_pk_bf16_f32 %0,%1,%2" : "=v"(w7) : "v"(sacc[14]), "v"(sacc[15]));
        asm("v_permlane32_swap_b32 %0, %1" : "+v"(w0), "+v"(w2));
        asm("v_permlane32_swap_b32 %0, %1" : "+v"(w1), "+v"(w3));
        asm("v_permlane32_swap_b32 %0, %1" : "+v"(w4), "+v"(w6));
        asm("v_permlane32_swap_b32 %0, %1" : "+v"(w5), "+v"(w7));
        union { uint32_t u[4]; bf16x8 v; } p0u, p1u;
        p0u.u[0] = w0; p0u.u[1] = w1; p0u.u[2] = w2; p0u.u[3] = w3;
        p1u.u[0] = w4; p1u.u[1] = w5; p1u.u[2] = w6; p1u.u[3] = w7;

        // O^T += V^T * P^T
        __builtin_amdgcn_s_setprio(1);
#pragma unroll
        for (int kk = 0; kk < 2; ++kk) {
            const bf16x8 pf = kk ? p1u.v : p0u.v;
#pragma unroll
            for (int ch = 0; ch < 8; ++ch) {
                const bf16x8 vf = *(const bf16x8*)(Vb + (kk * 8 + ch) * 1024 + lane16);
                o[ch] = __builtin_amdgcn_mfma_f32_32x32x16_bf16(vf, pf, o[ch], 0, 0, 0);
            }
        }
        __builtin_amdgcn_s_setprio(0);

        asm volatile("s_waitcnt vmcnt(0)" ::: "memory");
        __syncthreads();
        buf ^= 1;
    }

    lrun += __shfl_xor(lrun, 32, 64);

    float scale = 1.0f;
    u16* ab;
    const int qm = (w << 5) + l31;
    if (nch == 1) {
        scale = (lrun > 0.0f) ? 1.0f / lrun : 0.0f;
        ab = attnb + ((size_t)(b * 2048 + g + m * s)) * 1024 + h * 256;
    } else {
        if (h5 == 0 && m < LQ) {
            const int colid = b * 81 + colg;
            mlbuf[(size_t)((colid * 8 + chunk) * 256) + qm * 2]     = mrun;
            mlbuf[(size_t)((colid * 8 + chunk) * 256) + qm * 2 + 1] = lrun;
        }
        if (chunk == 0)
            ab = attnb + ((size_t)(b * 2048 + g + m * s)) * 1024 + h * 256;
        else
            ab = partO_addr(partLo, partHi, b * 94 + exb + chunk - 1) + (size_t)qm * 256;
    }

    if (m < LQ) {
#pragma unroll
        for (int ch = 0; ch < 8; ++ch) {
#pragma unroll
            for (int g2 = 0; g2 < 4; ++g2) {
                ushort4 wv4;
                wv4.x = f2bf(o[ch][g2 * 4 + 0] * scale);
                wv4.y = f2bf(o[ch][g2 * 4 + 1] * scale);
                wv4.z = f2bf(o[ch][g2 * 4 + 2] * scale);
                wv4.w = f2bf(o[ch][g2 * 4 + 3] * scale);
                *(ushort4*)(ab + ch * 32 + 8 * g2 + 4 * h5) = wv4;
            }
        }
    }
}

// ---------------- combine chunked columns ----------------
__global__ __launch_bounds__(256)
void combine_kernel(const u16* __restrict__ partLo, const u16* __restrict__ partHi,
                    const float* __restrict__ mlbuf, u16* __restrict__ attnb) {
    static constexpr int MCc[24] = {0,14,18,22,26,28,30,32,34,36,38,40,
                                    40,40,40,40,40,40,40,40,40,40,40,40};
    static constexpr int CGc[24] = {0,16,22,28,34,37,40,43,46,49,52,55,
                                    57,59,61,63,65,67,69,71,73,75,77,79};
    static constexpr int EXc[24] = {0,56,64,72,80,82,84,86,88,90,92,94,
                                    94,94,94,94,94,94,94,94,94,94,94,94};
    const int b = blockIdx.x & 1;
    int rb = blockIdx.x >> 1;
    int p = 0, base = 0, colg = 0, exb = 0;
#pragma unroll
    for (int i = 1; i < 24; ++i)
        if (rb >= MCc[i]) { p = i; base = MCc[i]; colg = CGc[i]; exb = EXc[i]; }
    rb -= base;

    int col = 0, nch = 0;
    for (int c = T_nc[p] - 1; c >= 0; --c) {
        int nb, ta, n;
        col_geom(p, c, nb, ta, n);
        const int nc2 = (n + 7) >> 3;
        if (nc2 > 1) {
            if (rb == 0) { col = c; nch = nc2; break; }
            --rb;
        }
        ++colg; exb += nc2 - 1;
    }
    const int h = T_h[p], g = T_g[p];
    const int s = (h == 0) ? 1 : (h == 1) ? 3 : (h == 2) ? 7 : 13;
    const int LQ = T_LQ[p];
    const int colid = b * 81 + colg;
    const float c2 = 0.09016844f;

    const int t = threadIdx.x;
    const int q = t >> 1, dpart = (t & 1) * 128;
    const int m = (col << 7) + q;

    float mj[8], lj[8];
#pragma unroll
    for (int j5 = 0; j5 < 8; ++j5) {
        if (j5 < nch) {
            mj[j5] = mlbuf[(size_t)((colid * 8 + j5) * 256) + q * 2];
            lj[j5] = mlbuf[(size_t)((colid * 8 + j5) * 256) + q * 2 + 1];
        } else { mj[j5] = -3.0e38f; lj[j5] = 0.0f; }
    }
    float M = -3.0e38f;
#pragma unroll
    for (int j5 = 0; j5 < 8; ++j5) if (j5 < nch) M = fmaxf(M, mj[j5]);
    float L = 0.0f, al[8];
#pragma unroll
    for (int j5 = 0; j5 < 8; ++j5) {
        al[j5] = (j5 < nch) ? __builtin_amdgcn_exp2f((mj[j5] - M) * c2) : 0.0f;
        L += lj[j5] * al[j5];
    }
    const float inv = (L > 0.0f) ? 1.0f / L : 0.0f;
#pragma unroll
    for (int j5 = 0; j5 < 8; ++j5) al[j5] *= inv;

    u16* dst = attnb + ((size_t)(b * 2048 + g + m * s)) * 1024 + h * 256 + dpart;

    for (int ss = 0; ss < 4; ++ss) {
        float acc32[32];
#pragma unroll
        for (int e = 0; e < 32; ++e) acc32[e] = 0.0f;
#pragma unroll
        for (int j5 = 0; j5 < 8; ++j5) {
            if (j5 >= nch) continue;
            const u16* src = (j5 == 0)
                ? (dst + ss * 32)
                : (partO_addr_c(partLo, partHi, b * 94 + exb + j5 - 1) + (size_t)q * 256 + dpart + ss * 32);
            const float sc = al[j5];
#pragma unroll
            for (int w4 = 0; w4 < 4; ++w4) {
                const uint4 pk = *(const uint4*)(src + w4 * 8);
                const u32 ww[4] = { pk.x, pk.y, pk.z, pk.w };
#pragma unroll
                for (int e = 0; e < 4; ++e) {
                    union { u32 u; float f; } lo2, hi2;
                    lo2.u = ww[e] << 16;
                    hi2.u = ww[e] & 0xffff0000u;
                    acc32[w4 * 8 + e * 2]     += sc * lo2.f;
                    acc32[w4 * 8 + e * 2 + 1] += sc * hi2.f;
                }
            }
        }
        if (m < LQ) {
#pragma unroll
            for (int w4 = 0; w4 < 4; ++w4) {
                uint4 pk;
                pk.x = (u32)f2bf(acc32[w4 * 8 + 0]) | ((u32)f2bf(acc32[w4 * 8 + 1]) << 16);
                pk.y = (u32)f2bf(acc32[w4 * 8 + 2]) | ((u32)f2bf(acc32[w4 * 8 + 3]) << 16);
                pk.z = (u32)f2bf(acc32[w4 * 8 + 4]) | ((u32)f2bf(acc32[w4 * 8 + 5]) << 16);
                pk.w = (u32)f2bf(acc32[w4 * 8 + 6]) | ((u32)f2bf(acc32[w4 * 8 + 7]) << 16);
                *(uint4*)(dst + ss * 32 + w4 * 8) = pk;
            }
        }
    }
}

// ---------------- output GEMM: out = attnb @ Wo^T + bo (f32), BK=64 + swizzle ----------
__global__ __launch_bounds__(256, 2)
void gemm_out(const u16* __restrict__ A, const u16* __restrict__ Bw,
              const float* __restrict__ bias, float* __restrict__ outp) {
    __shared__ __align__(16) u16 As[2][8192], Bs[2][4096];
    const int bid = blockIdx.x;
    const int xcd = bid & 7, slot = bid >> 3;
    const int m0 = (xcd * 4 + (slot & 3)) * 128;
    const int n0 = (slot >> 2) * 64;
    const int t = threadIdx.x;
    const int lane = t & 63;
    const int wid = t >> 6;
    const int wr = wid >> 1, wc = wid & 1;
    const int l15 = lane & 15, l4 = lane >> 4;

    f32x4 acc[4][2] = {};

    auto stage = [&](int buf, int kt) {
        const int kbase = kt * 64;
#pragma unroll
        for (int c2 = 0; c2 < 4; ++c2) {
            const int p = c2 * 4096 + t * 16;
            const int row = p >> 7;
            const int cs = ((p >> 4) & 7) ^ (row & 7);
            g2l16(A + (size_t)(m0 + row) * 1024 + kbase + cs * 8, (char*)As[buf] + p);
        }
#pragma unroll
        for (int c2 = 0; c2 < 2; ++c2) {
            const int p = c2 * 4096 + t * 16;
            const int row = p >> 7;
            const int cs = ((p >> 4) & 7) ^ (row & 7);
            g2l16(Bw + (size_t)(n0 + row) * 1024 + kbase + cs * 8, (char*)Bs[buf] + p);
        }
    };

    stage(0, 0);
    asm volatile("s_waitcnt vmcnt(0)" ::: "memory");
    __syncthreads();

    int cur = 0;
    for (int kt = 0; kt < 16; ++kt) {
        if (kt + 1 < 16) stage(cur ^ 1, kt + 1);
#pragma unroll
        for (int kk = 0; kk < 2; ++kk) {
            bf16x8 af[4], bfr[2];
#pragma unroll
            for (int mi = 0; mi < 4; ++mi) {
                const int row = wr * 64 + mi * 16 + l15;
                af[mi] = *(const bf16x8*)((const char*)As[cur] + row * 128 + (((kk * 4 + l4) ^ (row & 7)) << 4));
            }
#pragma unroll
            for (int ni = 0; ni < 2; ++ni) {
                const int row = wc * 32 + ni * 16 + l15;
                bfr[ni] = *(const bf16x8*)((const char*)Bs[cur] + row * 128 + (((kk * 4 + l4) ^ (row & 7)) << 4));
            }
            __builtin_amdgcn_s_setprio(1);
#pragma unroll
            for (int mi = 0; mi < 4; ++mi)
#pragma unroll
                for (int ni = 0; ni < 2; ++ni)
                    acc[mi][ni] = __builtin_amdgcn_mfma_f32_16x16x32_bf16(af[mi], bfr[ni], acc[mi][ni], 0, 0, 0);
            __builtin_amdgcn_s_setprio(0);
        }
        asm volatile("s_waitcnt vmcnt(0)" ::: "memory");
        __syncthreads();
        cur ^= 1;
    }

    const int mbase = m0 + wr * 64 + l4 * 4;
    const int nbase = n0 + wc * 32 + l15;
#pragma unroll
    for (int ni = 0; ni < 2; ++ni) {
        const int n = nbase + ni * 16;
        const float bv = bias[n];
#pragma unroll
        for (int mi = 0; mi < 4; ++mi) {
            const int mrow = mbase + mi * 16;
#pragma unroll
            for (int r = 0; r < 4; ++r)
                outp[(size_t)(mrow + r) * 1024 + n] = acc[mi][ni][r] + bv;
        }
    }
}

extern "C" void kernel_launch(void* const* d_in, const int* in_sizes, int n_in,
                              void* d_out, int out_size, void* d_ws, size_t ws_size,
                              hipStream_t stream) {
    const float* x   = (const float*)d_in[0];
    const float* Wqk = (const float*)d_in[1];
    const float* bqk = (const float*)d_in[2];
    const float* Wv  = (const float*)d_in[3];
    const float* bv  = (const float*)d_in[4];
    const float* Wo  = (const float*)d_in[5];
    const float* bo  = (const float*)d_in[6];
    float* out = (float*)d_out;

    u16* ws     = (u16*)d_ws;
    u16* xb     = ws;             // 4,194,304 (dead after gemm_qkv -> attnb overlay)
    u16* wqkb   = ws + 4194304;   // 1,048,576 (dead after gemm_qkv -> partHi overlay)
    u16* wvb    = ws + 5242880;   // 1,048,576 (dead after gemm_qkv)
    u16* wob    = ws + 6291456;   // 1,048,576 (live until gemm_out)
    u16* qkb    = ws + 7340032;   // 4,194,304 (dead after repack_kv -> partLo overlay)
    u16* vb     = ws + 11534336;  // 4,194,304 (dead after repack_kv)
    u16* kpack  = ws + 15728640;  // 4,341,760
    u16* vpack  = ws + 20070400;  // 4,341,760 (ends 24,412,160 u16 = 48.8 MB)
    u16* attnb  = ws;             // overlays xb
    u16* partLo = ws + 7340032;   // 128 slots x 32768 u16 (overlays qkb)
    u16* partHi = ws + 4194304;   // 60 slots (overlays wqkb+wvb)
    float* mlbuf = (float*)d_out; // d_out dead until gemm_out

    cvt_kernel<<<7168, 256, 0, stream>>>(x, Wqk, Wv, Wo, ws);
    gemm_qkv<<<512, 256, 0, stream>>>(xb, wqkb, wvb, bqk, bv, qkb, vb);
    repack_kv<<<530, 256, 0, stream>>>(qkb, vb, kpack, vpack);
    attn_kernel<<<424, 256, 0, stream>>>(kpack, vpack, attnb, partLo, partHi, mlbuf);
    combine_kernel<<<80, 256, 0, stream>>>(partLo, partHi, mlbuf, attnb);
    gemm_out<<<512, 256, 0, stream>>>(attnb, wob, bo, out);
}

// Round 14
// 112.069 us; speedup vs baseline: 1.1742x; 1.0018x over previous
//
#include <hip/hip_runtime.h>
#include <cstdint>
#include <cstddef>

typedef unsigned short u16;
typedef uint32_t u32;
typedef __bf16 bf16x8 __attribute__((ext_vector_type(8)));
typedef float f32x4 __attribute__((ext_vector_type(4)));
typedef float f32x16 __attribute__((ext_vector_type(16)));

typedef __attribute__((address_space(1))) void gvoid;
typedef __attribute__((address_space(3))) void lvoid;

__device__ __forceinline__ void g2l16(const void* g, void* l) {
    __builtin_amdgcn_global_load_lds((gvoid*)g, (lvoid*)l, 16, 0, 0);
}

__device__ __forceinline__ u16 f2bf(float f) {
    union { float f; uint32_t u; } v;
    v.f = f;
    uint32_t r = (v.u + 0x7FFFu + ((v.u >> 16) & 1u)) >> 16;
    return (u16)r;
}

// ================= compressed-class problem tables (per batch: 24 problems) ==============
__device__ const int T_h[24]  = {0, 1,1,1, 2,2,2,2,2,2,2, 3,3,3,3,3,3,3,3,3,3,3,3,3};
__device__ const int T_g[24]  = {0, 0,1,2, 0,1,2,3,4,5,6, 0,1,2,3,4,5,6,7,8,9,10,11,12};
__device__ const int T_qt[24] = {0, 64,86,108, 130,140,150,160,170,180,190,
                                 200,205,210,215,220,225,230,235,240,245,250,255,260};
__device__ const int T_LQ[24] = {2048, 683,683,682, 293,293,293,293,292,292,292,
                                 158,158,158,158,158,158,158,157,157,157,157,157,157};
__device__ const int T_ktB[24]= {0, 64,86,108, 140,150,160,170,180,190,130,
                                 245,250,255,260,200,205,210,215,220,225,230,235,240};
__device__ const int T_LkB[24]= {2048, 683,683,682, 293,293,293,292,292,292,293,
                                 157,157,157,157,158,158,158,158,158,158,158,157,157};
__device__ const int T_cB[24] = {1, -341,-341,-341, -146,-146,-146,-146,-146,-146,-145,
                                 -79,-79,-79,-79,-78,-78,-78,-78,-78,-78,-78,-78,-78};
__device__ const int T_ktA[24]= {0, 108,64,86, 180,190,130,140,150,160,170,
                                 215,220,225,230,235,240,245,250,255,260,200,205,210};
__device__ const int T_LkA[24]= {0, 682,683,683, 292,292,293,293,293,293,292,
                                 158,158,158,158,157,157,157,157,157,157,158,158,158};
__device__ const int T_cA[24] = {0, -342,-341,-341, -147,-147,-146,-146,-146,-146,-146,
                                 -79,-79,-79,-79,-79,-79,-79,-79,-79,-79,-78,-78,-78};
__device__ const int T_dA[24] = {0, 0,1,1, 0,0,1,1,1,1,1, 0,0,0,0,0,0,0,0,0,0,1,1,1};
__device__ const int T_nc[24] = {16, 6,6,6, 3,3,3,3,3,3,3, 2,2,2,2,2,2,2,2,2,2,2,2,2};

__device__ __forceinline__ void col_geom(int p, int c, int& ntB, int& tA0, int& nt) {
    const int LQ = T_LQ[p];
    const int Mc = c << 7;
    int mmax = Mc + 128; if (mmax > LQ) mmax = LQ; mmax -= 1;
    int jB = mmax + T_cB[p];
    if (jB < 0) jB = 0;
    if (jB > T_LkB[p]) jB = T_LkB[p];
    ntB = (jB + 31) >> 5;
    int jlo = Mc + T_cA[p]; if (jlo < 0) jlo = 0;
    int jhi = mmax + T_dA[p];
    if (jhi > T_LkA[p]) jhi = T_LkA[p];
    tA0 = jlo >> 5;
    int ntA = 0;
    if (jhi > jlo) ntA = ((jhi + 31) >> 5) - tA0;
    nt = ntB + ntA;
}

__device__ __forceinline__ u16* partO_addr(u16* lo, u16* hi, int slot) {
    return (slot < 128) ? (lo + (size_t)slot * 32768) : (hi + (size_t)(slot - 128) * 32768);
}
__device__ __forceinline__ const u16* partO_addr_c(const u16* lo, const u16* hi, int slot) {
    return (slot < 128) ? (lo + (size_t)slot * 32768) : (hi + (size_t)(slot - 128) * 32768);
}

// ---------------- fp32 -> bf16 conversion of x, Wqk, Wv, Wo into ws ----------------
__global__ __launch_bounds__(256)
void cvt_kernel(const float* __restrict__ x, const float* __restrict__ wqk,
                const float* __restrict__ wv, const float* __restrict__ wo,
                u16* __restrict__ out) {
    int i = (blockIdx.x * 256 + threadIdx.x) * 4;
    const float* src;
    int off;
    if (i < 4194304)      { src = x;   off = 0; }
    else if (i < 5242880) { src = wqk; off = 4194304; }
    else if (i < 6291456) { src = wv;  off = 5242880; }
    else                  { src = wo;  off = 6291456; }
    float4 v = *(const float4*)(src + (i - off));
    ushort4 o;
    o.x = f2bf(v.x); o.y = f2bf(v.y); o.z = f2bf(v.z); o.w = f2bf(v.w);
    *(ushort4*)(out + i) = o;
}

// ---------------- fused QK+V projection GEMM, row-major bf16 outputs ----------------
// BK=64, XOR-swizzled staging (chunk ^= row&7 within 128B rows) -> conflict-free ds_read_b128.
// 2-D XCD map: xcd = (m-group 0..3) x (n-half 0..1).
__global__ __launch_bounds__(256, 2)
void gemm_qkv(const u16* __restrict__ A, const u16* __restrict__ Bq, const u16* __restrict__ Bv,
              const float* __restrict__ bq, const float* __restrict__ bv,
              u16* __restrict__ qkb, u16* __restrict__ vb) {
    __shared__ __align__(16) u16 As[2][8192], Bqs[2][4096], Bvs[2][4096];
    const int bid = blockIdx.x;
    const int xcd = bid & 7, slot = bid >> 3;
    const int m0 = ((xcd >> 1) * 8 + (slot & 7)) * 128;
    const int n0 = ((xcd & 1) * 8 + (slot >> 3)) * 64;
    const int t = threadIdx.x;
    const int lane = t & 63;
    const int wid = t >> 6;
    const int wr = wid >> 1, wc = wid & 1;
    const int l15 = lane & 15, l4 = lane >> 4;

    f32x4 aq[4][2] = {}, av[4][2] = {};

    auto stage = [&](int buf, int kt) {
        const int kbase = kt * 64;
#pragma unroll
        for (int c2 = 0; c2 < 4; ++c2) {
            const int p = c2 * 4096 + t * 16;
            const int row = p >> 7;
            const int cs = ((p >> 4) & 7) ^ (row & 7);
            g2l16(A + (size_t)(m0 + row) * 1024 + kbase + cs * 8, (char*)As[buf] + p);
        }
#pragma unroll
        for (int c2 = 0; c2 < 2; ++c2) {
            const int p = c2 * 4096 + t * 16;
            const int row = p >> 7;
            const int cs = ((p >> 4) & 7) ^ (row & 7);
            const size_t so = (size_t)(n0 + row) * 1024 + kbase + cs * 8;
            g2l16(Bq + so, (char*)Bqs[buf] + p);
            g2l16(Bv + so, (char*)Bvs[buf] + p);
        }
    };

    stage(0, 0);
    asm volatile("s_waitcnt vmcnt(0)" ::: "memory");
    __syncthreads();

    int cur = 0;
    for (int kt = 0; kt < 16; ++kt) {
        if (kt + 1 < 16) stage(cur ^ 1, kt + 1);
#pragma unroll
        for (int kk = 0; kk < 2; ++kk) {
            bf16x8 af[4], bfq[2], bfv[2];
#pragma unroll
            for (int mi = 0; mi < 4; ++mi) {
                const int row = wr * 64 + mi * 16 + l15;
                af[mi] = *(const bf16x8*)((const char*)As[cur] + row * 128 + (((kk * 4 + l4) ^ (row & 7)) << 4));
            }
#pragma unroll
            for (int ni = 0; ni < 2; ++ni) {
                const int row = wc * 32 + ni * 16 + l15;
                const int co = row * 128 + (((kk * 4 + l4) ^ (row & 7)) << 4);
                bfq[ni] = *(const bf16x8*)((const char*)Bqs[cur] + co);
                bfv[ni] = *(const bf16x8*)((const char*)Bvs[cur] + co);
            }
            __builtin_amdgcn_s_setprio(1);
#pragma unroll
            for (int mi = 0; mi < 4; ++mi)
#pragma unroll
                for (int ni = 0; ni < 2; ++ni) {
                    aq[mi][ni] = __builtin_amdgcn_mfma_f32_16x16x32_bf16(af[mi], bfq[ni], aq[mi][ni], 0, 0, 0);
                    av[mi][ni] = __builtin_amdgcn_mfma_f32_16x16x32_bf16(af[mi], bfv[ni], av[mi][ni], 0, 0, 0);
                }
            __builtin_amdgcn_s_setprio(0);
        }
        asm volatile("s_waitcnt vmcnt(0)" ::: "memory");
        __syncthreads();
        cur ^= 1;
    }

    const int mbase = m0 + wr * 64 + l4 * 4;
    const int nbase = n0 + wc * 32 + l15;
#pragma unroll
    for (int ni = 0; ni < 2; ++ni) {
        const int n = nbase + ni * 16;
        const float bq_ = bq[n];
        const float bv_ = bv[n];
#pragma unroll
        for (int mi = 0; mi < 4; ++mi) {
            const int mrow = mbase + mi * 16;
#pragma unroll
            for (int r = 0; r < 4; ++r) {
                qkb[(size_t)(mrow + r) * 1024 + n] = f2bf(aq[mi][ni][r] + bq_);
                vb [(size_t)(mrow + r) * 1024 + n] = f2bf(av[mi][ni][r] + bv_);
            }
        }
    }
}

// ---------------- tile decode for repack kernel ----------------
__device__ __forceinline__ void tile_decode(int tt, int& h, int& cls, int& jt, int& LK) {
    if (tt < 64)       { h = 0; cls = 0;               jt = tt;              LK = 2048; }
    else if (tt < 130) { h = 1; cls = (tt - 64) / 22;  jt = (tt - 64) % 22;  LK = (cls < 2) ? 683 : 682; }
    else if (tt < 200) { h = 2; cls = (tt - 130) / 10; jt = (tt - 130) % 10; LK = (cls < 4) ? 293 : 292; }
    else               { h = 3; cls = (tt - 200) / 5;  jt = (tt - 200) % 5;  LK = (cls < 7) ? 158 : 157; }
}

// ---------------- repack K and V into fragment-major class-tile layouts (merged) ---------
__global__ __launch_bounds__(256)
void repack_kv(const u16* __restrict__ qkb, const u16* __restrict__ vb,
               u16* __restrict__ kpack, u16* __restrict__ vpack) {
    __shared__ __align__(16) unsigned char sm[32768];   // K 16KB | V 16KB
    const int bid = blockIdx.x;
    const int b = bid & 1;
    const int tt = bid >> 1;
    int h, cls, jt, LK;
    tile_decode(tt, h, cls, jt, LK);
    const int s = (h == 0) ? 1 : (h == 1) ? 3 : (h == 2) ? 7 : 13;
    const int j0 = jt * 32;
    int nval = LK - j0; if (nval > 32) nval = 32;
    const int t = threadIdx.x;

#pragma unroll
    for (int i2 = 0; i2 < 4; ++i2) {
        const int p = i2 * 4096 + t * 16;
        const int j = p >> 9;
        const int cb = (p & 511) ^ ((j & 31) << 4);
        const int jj = (j < nval) ? j : (nval - 1);
        const size_t gofs = (size_t)((b * 2048 + cls + (j0 + jj) * s) * 1024 + h * 256) + (cb >> 1);
        g2l16(qkb + gofs, sm + p);
        g2l16(vb  + gofs, sm + 16384 + p);
    }
    asm volatile("s_waitcnt vmcnt(0)" ::: "memory");
    __syncthreads();
    if (nval < 32) {
        const int pb = 16384 + nval * 512;
        for (int off = pb + t * 16; off < 32768; off += 4096) {
            uint4 z; z.x = 0; z.y = 0; z.z = 0; z.w = 0;
            *(uint4*)(sm + off) = z;
        }
        __syncthreads();
    }
    const size_t tb = (size_t)(b * 265 + tt) * 8192;
    // kpack: 8 consecutive elems = same j, d0..d0+7
#pragma unroll
    for (int i2 = 0; i2 < 4; ++i2) {
        const int o = (i2 * 256 + t) * 8;
        const int dc = o >> 9;
        const int idx = (o >> 3) & 63;
        const int j = idx & 31;
        const int d0 = dc * 16 + (idx >> 5) * 8;
        const uint4 pk = *(const uint4*)(sm + j * 512 + ((d0 * 2) ^ ((j & 31) << 4)));
        *(uint4*)(kpack + tb + o) = pk;
    }
    // vpack: transposed gather from LDS
#pragma unroll
    for (int i2 = 0; i2 < 4; ++i2) {
        const int o = (i2 * 256 + t) * 8;
        const int slot2 = o >> 9;
        const int idx = (o >> 3) & 63;
        const int jb = (slot2 >> 3) * 16 + (idx >> 5) * 8;
        const int d = (slot2 & 7) * 32 + (idx & 31);
        u32 wpk[4];
#pragma unroll
        for (int e2 = 0; e2 < 4; ++e2) {
            const int j1 = jb + e2 * 2, j2 = j1 + 1;
            const u16 a0 = *(const u16*)(sm + 16384 + j1 * 512 + (((d >> 3) ^ (j1 & 31)) << 4) + (d & 7) * 2);
            const u16 a1 = *(const u16*)(sm + 16384 + j2 * 512 + (((d >> 3) ^ (j2 & 31)) << 4) + (d & 7) * 2);
            wpk[e2] = (u32)a0 | ((u32)a1 << 16);
        }
        uint4 pk; pk.x = wpk[0]; pk.y = wpk[1]; pk.z = wpk[2]; pk.w = wpk[3];
        *(uint4*)(vpack + tb + o) = pk;
    }
}

// ---------------- compressed flash attention: XCD-pinned, K triple-buffered (depth-2) ----
// LDS: K[3][16KB] + V[2][16KB] = 80KB -> exactly 2 blocks/CU. Counted vmcnt(4): only the
// newest K prefetch stays in flight across the barrier; never drain to 0 in the loop.
__global__ __launch_bounds__(256, 2)
void attn_kernel(const u16* __restrict__ kpack, const u16* __restrict__ vpack,
                 u16* __restrict__ attnb, u16* __restrict__ partLo, u16* __restrict__ partHi,
                 float* __restrict__ mlbuf) {
    __shared__ __align__(16) unsigned char sm[81920];   // K0|K1|K2|V0|V1 (16KB each)
    static constexpr int CGc[24] = {0,16,22,28,34,37,40,43,46,49,52,55,
                                    57,59,61,63,65,67,69,71,73,75,77,79};
    static constexpr int EXc[24] = {0,56,64,72,80,82,84,86,88,90,92,94,
                                    94,94,94,94,94,94,94,94,94,94,94,94};
    static constexpr int Tpc[24] = {72,14,14,14,5,5,5,5,5,5,5,2,2,2,2,2,2,2,2,2,2,2,2,2};

    const int bid = blockIdx.x;
    const int xcd = bid & 7, slot = bid >> 3;
    const int b = xcd & 1, quad = xcd >> 1;
    int hsel, hcb;
    if (quad == 0) {
        if (slot >= 37) return;
        hsel = 0; hcb = slot;
    } else if (quad == 1) {
        if (slot < 35)      { hsel = 0; hcb = 37 + slot; }
        else if (slot < 43) { hsel = 3; hcb = slot - 35; }
        else return;
    } else if (quad == 2) {
        if (slot >= 42) return;
        hsel = 1; hcb = slot;
    } else {
        if (slot < 35)      { hsel = 2; hcb = slot; }
        else if (slot < 53) { hsel = 3; hcb = 8 + (slot - 35); }
        else return;
    }
    int p = (hsel == 0) ? 0 : (hsel == 1) ? 1 : (hsel == 2) ? 4 : 11;
    int rb = hcb;
    while (rb >= Tpc[p]) { rb -= Tpc[p]; ++p; }
    int colg = CGc[p], exb = EXc[p];

    const int LQ = T_LQ[p];
    const int cB = T_cB[p], cA = T_cA[p], dA = T_dA[p];
    const int LKB = T_LkB[p], LKA = T_LkA[p];
    const int ktB = T_ktB[p], ktA = T_ktA[p];
    const int h = T_h[p], g = T_g[p], nc = T_nc[p], qt0 = T_qt[p];
    const int s = (h == 0) ? 1 : (h == 1) ? 3 : (h == 2) ? 7 : 13;

    int col = 0, chunk = 0, ntB = 0, tA0 = 0, nt = 0;
    for (int c = nc - 1; c >= 0; --c) {
        const int Mc = c << 7;
        int mmax = Mc + 128; if (mmax > LQ) mmax = LQ; mmax -= 1;
        int jB = mmax + cB; if (jB < 0) jB = 0; if (jB > LKB) jB = LKB;
        const int nb = (jB + 31) >> 5;
        int jlo = Mc + cA; if (jlo < 0) jlo = 0;
        int jhi = mmax + dA; if (jhi > LKA) jhi = LKA;
        const int ta = jlo >> 5;
        const int na = (jhi > jlo) ? (((jhi + 31) >> 5) - ta) : 0;
        const int n = nb + na;
        const int nch2 = (n + 7) >> 3;
        if (rb < nch2) { col = c; chunk = rb; ntB = nb; tA0 = ta; nt = n; break; }
        rb -= nch2; ++colg; exb += nch2 - 1;
    }
    const int nch = (nt + 7) >> 3;
    const int PBi = b * 265;

    const int t = threadIdx.x;
    const int w = t >> 6;
    const int l = t & 63;
    const int l31 = l & 31, h5 = l >> 5;
    const int m = (col << 7) + (w << 5) + l31;     // compressed query index
    const float c2 = 0.09016844f;                  // (1/16) * log2(e)
    const int lane16 = l * 16;                     // byte offset in packed tile

    // Q fragments from kpack class-g list tile (coalesced)
    bf16x8 qf[16];
    {
        const u16* qb = kpack + (size_t)(PBi + qt0 + col * 4 + w) * 8192 + l * 8;
#pragma unroll
        for (int dc = 0; dc < 16; ++dc)
            qf[dc] = *(const bf16x8*)(qb + dc * 512);
    }

    const int tt0 = chunk * 8;
    int tt1 = tt0 + 8; if (tt1 > nt) tt1 = nt;

    auto tileof = [&](int tv) -> int {
        if (tv >= tt1) tv = tt1 - 1;               // clamp (redundant re-stage, keeps counts fixed)
        return (tv < ntB) ? (ktB + tv) : (ktA + tA0 + (tv - ntB));
    };
    auto stageK = [&](int tv, int kb) {
        const size_t tb = (size_t)(PBi + tileof(tv)) * 8192;
        unsigned char* Kd = sm + kb * 16384;
#pragma unroll
        for (int i2 = 0; i2 < 4; ++i2) {
            const int off = i2 * 4096 + t * 16;
            g2l16(kpack + tb + (off >> 1), Kd + off);
        }
    };
    auto stageV = [&](int tv, int vbi) {
        const size_t tb = (size_t)(PBi + tileof(tv)) * 8192;
        unsigned char* Vd = sm + 49152 + vbi * 16384;
#pragma unroll
        for (int i2 = 0; i2 < 4; ++i2) {
            const int off = i2 * 4096 + t * 16;
            g2l16(vpack + tb + (off >> 1), Vd + off);
        }
    };

    f32x16 o[8] = {};
    float mrun = -3.0e38f, lrun = 0.0f;

    // prologue: V(tt0), K(tt0), K(tt0+1) in flight; wait all but K(tt0+1)'s 4
    stageV(tt0, 0);
    stageK(tt0, 0);
    stageK(tt0 + 1, 1);
    asm volatile("s_waitcnt vmcnt(4)" ::: "memory");
    __syncthreads();

    for (int tv = tt0; tv < tt1; ++tv) {
        const int it = tv - tt0;
        // issue next V first, then next-next K (newest 4 = that K)
        stageV(tv + 1, (it + 1) & 1);
        stageK(tv + 2, (it + 2) % 3);

        int j0, lo, hi;
        if (tv < ntB) { j0 = tv << 5; lo = -100000; hi = cB; }
        else { const int ta = tA0 + tv - ntB; j0 = ta << 5; lo = cA; hi = dA; }

        const unsigned char* Kb = sm + ((it % 3) * 16384);
        const unsigned char* Vb = sm + 49152 + ((it & 1) * 16384);

        // S^T = K * Q^T
        f32x16 sacc = {};
        __builtin_amdgcn_s_setprio(1);
#pragma unroll
        for (int dc = 0; dc < 16; ++dc) {
            const bf16x8 kf = *(const bf16x8*)(Kb + dc * 1024 + lane16);
            sacc = __builtin_amdgcn_mfma_f32_32x32x16_bf16(kf, qf[dc], sacc, 0, 0, 0);
        }
        __builtin_amdgcn_s_setprio(0);

        // mask + online softmax, in place (lane-local; e = j - m)
        const int ebase = j0 - m;
        float tmax = -3.0e38f;
#pragma unroll
        for (int r = 0; r < 16; ++r) {
            const int km = (r & 3) + 8 * (r >> 2) + 4 * h5;
            const int e = ebase + km;
            const bool ok = (e >= lo) && (e < hi);
            sacc[r] = ok ? sacc[r] : -3.0e38f;
            tmax = fmaxf(tmax, sacc[r]);
        }
        tmax = fmaxf(tmax, __shfl_xor(tmax, 32, 64));
        if (!__all(tmax <= mrun + 8.0f)) {     // defer-max
            const float mnew = fmaxf(mrun, tmax);
            const float fsc = __builtin_amdgcn_exp2f((mrun - mnew) * c2);
            lrun *= fsc;
#pragma unroll
            for (int ch = 0; ch < 8; ++ch)
#pragma unroll
                for (int r = 0; r < 16; ++r)
                    o[ch][r] *= fsc;
            mrun = mnew;
        }
        float psum = 0.0f;
#pragma unroll
        for (int r = 0; r < 16; ++r) {
            const float pv = (sacc[r] > -1.0e37f) ? __builtin_amdgcn_exp2f((sacc[r] - mrun) * c2) : 0.0f;
            sacc[r] = pv;
            psum += pv;
        }
        lrun += psum;

        // P -> bf16 fragments: cvt_pk + permlane32_swap
        uint32_t w0, w1, w2, w3, w4, w5, w6, w7;
        asm("v_cvt_pk_bf16_f32 %0,%1,%2" : "=v"(w0) : "v"(sacc[0]),  "v"(sacc[1]));
        asm("v_cvt_pk_bf16_f32 %0,%1,%2" : "=v"(w1) : "v"(sacc[2]),  "v"(sacc[3]));
        asm("v_cvt_pk_bf16_f32 %0,%1,%2" : "=v"(w2) : "v"(sacc[4]),  "v"(sacc[5]));
        asm("v_cvt_pk_bf16_f32 %0,%1,%2" : "=v"(w3) : "v"(sacc[6]),  "v"(sacc[7]));
        asm("v_cvt_pk_bf16_f32 %0,%1,%2" : "=v"(w4) : "v"(sacc[8]),  "v"(sacc[9]));
        asm("v_cvt_pk_bf16_f32 %0,%1,%2" : "=v"(w5) : "v"(sacc[10]), "v"(sacc[11]));
        asm("v_cvt_pk_bf16_f32 %0,%1,%2" : "=v"(w6) : "v"(sacc[12]), "v"(sacc[13]));
        asm("v_cvt_pk_bf16_f32 %0,%1,%2" : "=v"(w7) : "v"(sacc[14]), "v"(sacc[15]));
        asm("v_permlane32_swap_b32 %0, %1" : "+v"(w0), "+v"(w2));
        asm("v_permlane32_swap_b32 %0, %1" : "+v"(w1), "+v"(w3));
        asm("v_permlane32_swap_b32 %0, %1" : "+v"(w4), "+v"(w6));
        asm("v_permlane32_swap_b32 %0, %1" : "+v"(w5), "+v"(w7));
        union { uint32_t u[4]; bf16x8 v; } p0u, p1u;
        p0u.u[0] = w0; p0u.u[1] = w1; p0u.u[2] = w2; p0u.u[3] = w3;
        p1u.u[0] = w4; p1u.u[1] = w5; p1u.u[2] = w6; p1u.u[3] = w7;

        // O^T += V^T * P^T
        __builtin_amdgcn_s_setprio(1);
#pragma unroll
        for (int kk = 0; kk < 2; ++kk) {
            const bf16x8 pf = kk ? p1u.v : p0u.v;
#pragma unroll
            for (int ch = 0; ch < 8; ++ch) {
                const bf16x8 vf = *(const bf16x8*)(Vb + (kk * 8 + ch) * 1024 + lane16);
                o[ch] = __builtin_amdgcn_mfma_f32_32x32x16_bf16(vf, pf, o[ch], 0, 0, 0);
            }
        }
        __builtin_amdgcn_s_setprio(0);

        // counted: only the just-issued K prefetch (4 loads) may remain in flight
        asm volatile("s_waitcnt vmcnt(4)" ::: "memory");
        __syncthreads();
    }

    lrun += __shfl_xor(lrun, 32, 64);

    float scale = 1.0f;
    u16* ab;
    const int qm = (w << 5) + l31;
    if (nch == 1) {
        scale = (lrun > 0.0f) ? 1.0f / lrun : 0.0f;
        ab = attnb + ((size_t)(b * 2048 + g + m * s)) * 1024 + h * 256;
    } else {
        if (h5 == 0 && m < LQ) {
            const int colid = b * 81 + colg;
            mlbuf[(size_t)((colid * 8 + chunk) * 256) + qm * 2]     = mrun;
            mlbuf[(size_t)((colid * 8 + chunk) * 256) + qm * 2 + 1] = lrun;
        }
        if (chunk == 0)
            ab = attnb + ((size_t)(b * 2048 + g + m * s)) * 1024 + h * 256;
        else
            ab = partO_addr(partLo, partHi, b * 94 + exb + chunk - 1) + (size_t)qm * 256;
    }

    if (m < LQ) {
#pragma unroll
        for (int ch = 0; ch < 8; ++ch) {
#pragma unroll
            for (int g2 = 0; g2 < 4; ++g2) {
                ushort4 wv4;
                wv4.x = f2bf(o[ch][g2 * 4 + 0] * scale);
                wv4.y = f2bf(o[ch][g2 * 4 + 1] * scale);
                wv4.z = f2bf(o[ch][g2 * 4 + 2] * scale);
                wv4.w = f2bf(o[ch][g2 * 4 + 3] * scale);
                *(ushort4*)(ab + ch * 32 + 8 * g2 + 4 * h5) = wv4;
            }
        }
    }
}

// ---------------- combine chunked columns ----------------
__global__ __launch_bounds__(256)
void combine_kernel(const u16* __restrict__ partLo, const u16* __restrict__ partHi,
                    const float* __restrict__ mlbuf, u16* __restrict__ attnb) {
    static constexpr int MCc[24] = {0,14,18,22,26,28,30,32,34,36,38,40,
                                    40,40,40,40,40,40,40,40,40,40,40,40};
    static constexpr int CGc[24] = {0,16,22,28,34,37,40,43,46,49,52,55,
                                    57,59,61,63,65,67,69,71,73,75,77,79};
    static constexpr int EXc[24] = {0,56,64,72,80,82,84,86,88,90,92,94,
                                    94,94,94,94,94,94,94,94,94,94,94,94};
    const int b = blockIdx.x & 1;
    int rb = blockIdx.x >> 1;
    int p = 0, base = 0, colg = 0, exb = 0;
#pragma unroll
    for (int i = 1; i < 24; ++i)
        if (rb >= MCc[i]) { p = i; base = MCc[i]; colg = CGc[i]; exb = EXc[i]; }
    rb -= base;

    int col = 0, nch = 0;
    for (int c = T_nc[p] - 1; c >= 0; --c) {
        int nb, ta, n;
        col_geom(p, c, nb, ta, n);
        const int nc2 = (n + 7) >> 3;
        if (nc2 > 1) {
            if (rb == 0) { col = c; nch = nc2; break; }
            --rb;
        }
        ++colg; exb += nc2 - 1;
    }
    const int h = T_h[p], g = T_g[p];
    const int s = (h == 0) ? 1 : (h == 1) ? 3 : (h == 2) ? 7 : 13;
    const int LQ = T_LQ[p];
    const int colid = b * 81 + colg;
    const float c2 = 0.09016844f;

    const int t = threadIdx.x;
    const int q = t >> 1, dpart = (t & 1) * 128;
    const int m = (col << 7) + q;

    float mj[8], lj[8];
#pragma unroll
    for (int j5 = 0; j5 < 8; ++j5) {
        if (j5 < nch) {
            mj[j5] = mlbuf[(size_t)((colid * 8 + j5) * 256) + q * 2];
            lj[j5] = mlbuf[(size_t)((colid * 8 + j5) * 256) + q * 2 + 1];
        } else { mj[j5] = -3.0e38f; lj[j5] = 0.0f; }
    }
    float M = -3.0e38f;
#pragma unroll
    for (int j5 = 0; j5 < 8; ++j5) if (j5 < nch) M = fmaxf(M, mj[j5]);
    float L = 0.0f, al[8];
#pragma unroll
    for (int j5 = 0; j5 < 8; ++j5) {
        al[j5] = (j5 < nch) ? __builtin_amdgcn_exp2f((mj[j5] - M) * c2) : 0.0f;
        L += lj[j5] * al[j5];
    }
    const float inv = (L > 0.0f) ? 1.0f / L : 0.0f;
#pragma unroll
    for (int j5 = 0; j5 < 8; ++j5) al[j5] *= inv;

    u16* dst = attnb + ((size_t)(b * 2048 + g + m * s)) * 1024 + h * 256 + dpart;

    for (int ss = 0; ss < 4; ++ss) {
        float acc32[32];
#pragma unroll
        for (int e = 0; e < 32; ++e) acc32[e] = 0.0f;
#pragma unroll
        for (int j5 = 0; j5 < 8; ++j5) {
            if (j5 >= nch) continue;
            const u16* src = (j5 == 0)
                ? (dst + ss * 32)
                : (partO_addr_c(partLo, partHi, b * 94 + exb + j5 - 1) + (size_t)q * 256 + dpart + ss * 32);
            const float sc = al[j5];
#pragma unroll
            for (int w4 = 0; w4 < 4; ++w4) {
                const uint4 pk = *(const uint4*)(src + w4 * 8);
                const u32 ww[4] = { pk.x, pk.y, pk.z, pk.w };
#pragma unroll
                for (int e = 0; e < 4; ++e) {
                    union { u32 u; float f; } lo2, hi2;
                    lo2.u = ww[e] << 16;
                    hi2.u = ww[e] & 0xffff0000u;
                    acc32[w4 * 8 + e * 2]     += sc * lo2.f;
                    acc32[w4 * 8 + e * 2 + 1] += sc * hi2.f;
                }
            }
        }
        if (m < LQ) {
#pragma unroll
            for (int w4 = 0; w4 < 4; ++w4) {
                uint4 pk;
                pk.x = (u32)f2bf(acc32[w4 * 8 + 0]) | ((u32)f2bf(acc32[w4 * 8 + 1]) << 16);
                pk.y = (u32)f2bf(acc32[w4 * 8 + 2]) | ((u32)f2bf(acc32[w4 * 8 + 3]) << 16);
                pk.z = (u32)f2bf(acc32[w4 * 8 + 4]) | ((u32)f2bf(acc32[w4 * 8 + 5]) << 16);
                pk.w = (u32)f2bf(acc32[w4 * 8 + 6]) | ((u32)f2bf(acc32[w4 * 8 + 7]) << 16);
                *(uint4*)(dst + ss * 32 + w4 * 8) = pk;
            }
        }
    }
}

// ---------------- output GEMM: out = attnb @ Wo^T + bo (f32), BK=64 + swizzle ----------
__global__ __launch_bounds__(256, 3)
void gemm_out(const u16* __restrict__ A, const u16* __restrict__ Bw,
              const float* __restrict__ bias, float* __restrict__ outp) {
    __shared__ __align__(16) u16 As[2][8192], Bs[2][4096];
    const int bid = blockIdx.x;
    const int xcd = bid & 7, slot = bid >> 3;
    const int m0 = (xcd * 4 + (slot & 3)) * 128;
    const int n0 = (slot >> 2) * 64;
    const int t = threadIdx.x;
    const int lane = t & 63;
    const int wid = t >> 6;
    const int wr = wid >> 1, wc = wid & 1;
    const int l15 = lane & 15, l4 = lane >> 4;

    f32x4 acc[4][2] = {};

    auto stage = [&](int buf, int kt) {
        const int kbase = kt * 64;
#pragma unroll
        for (int c2 = 0; c2 < 4; ++c2) {
            const int p = c2 * 4096 + t * 16;
            const int row = p >> 7;
            const int cs = ((p >> 4) & 7) ^ (row & 7);
            g2l16(A + (size_t)(m0 + row) * 1024 + kbase + cs * 8, (char*)As[buf] + p);
        }
#pragma unroll
        for (int c2 = 0; c2 < 2; ++c2) {
            const int p = c2 * 4096 + t * 16;
            const int row = p >> 7;
            const int cs = ((p >> 4) & 7) ^ (row & 7);
            g2l16(Bw + (size_t)(n0 + row) * 1024 + kbase + cs * 8, (char*)Bs[buf] + p);
        }
    };

    stage(0, 0);
    asm volatile("s_waitcnt vmcnt(0)" ::: "memory");
    __syncthreads();

    int cur = 0;
    for (int kt = 0; kt < 16; ++kt) {
        if (kt + 1 < 16) stage(cur ^ 1, kt + 1);
#pragma unroll
        for (int kk = 0; kk < 2; ++kk) {
            bf16x8 af[4], bfr[2];
#pragma unroll
            for (int mi = 0; mi < 4; ++mi) {
                const int row = wr * 64 + mi * 16 + l15;
                af[mi] = *(const bf16x8*)((const char*)As[cur] + row * 128 + (((kk * 4 + l4) ^ (row & 7)) << 4));
            }
#pragma unroll
            for (int ni = 0; ni < 2; ++ni) {
                const int row = wc * 32 + ni * 16 + l15;
                bfr[ni] = *(const bf16x8*)((const char*)Bs[cur] + row * 128 + (((kk * 4 + l4) ^ (row & 7)) << 4));
            }
            __builtin_amdgcn_s_setprio(1);
#pragma unroll
            for (int mi = 0; mi < 4; ++mi)
#pragma unroll
                for (int ni = 0; ni < 2; ++ni)
                    acc[mi][ni] = __builtin_amdgcn_mfma_f32_16x16x32_bf16(af[mi], bfr[ni], acc[mi][ni], 0, 0, 0);
            __builtin_amdgcn_s_setprio(0);
        }
        asm volatile("s_waitcnt vmcnt(0)" ::: "memory");
        __syncthreads();
        cur ^= 1;
    }

    const int mbase = m0 + wr * 64 + l4 * 4;
    const int nbase = n0 + wc * 32 + l15;
#pragma unroll
    for (int ni = 0; ni < 2; ++ni) {
        const int n = nbase + ni * 16;
        const float bv = bias[n];
#pragma unroll
        for (int mi = 0; mi < 4; ++mi) {
            const int mrow = mbase + mi * 16;
#pragma unroll
            for (int r = 0; r < 4; ++r)
                outp[(size_t)(mrow + r) * 1024 + n] = acc[mi][ni][r] + bv;
        }
    }
}

extern "C" void kernel_launch(void* const* d_in, const int* in_sizes, int n_in,
                              void* d_out, int out_size, void* d_ws, size_t ws_size,
                              hipStream_t stream) {
    const float* x   = (const float*)d_in[0];
    const float* Wqk = (const float*)d_in[1];
    const float* bqk = (const float*)d_in[2];
    const float* Wv  = (const float*)d_in[3];
    const float* bv  = (const float*)d_in[4];
    const float* Wo  = (const float*)d_in[5];
    const float* bo  = (const float*)d_in[6];
    float* out = (float*)d_out;

    u16* ws     = (u16*)d_ws;
    u16* xb     = ws;             // 4,194,304 (dead after gemm_qkv -> attnb overlay)
    u16* wqkb   = ws + 4194304;   // 1,048,576 (dead after gemm_qkv -> partHi overlay)
    u16* wvb    = ws + 5242880;   // 1,048,576 (dead after gemm_qkv)
    u16* wob    = ws + 6291456;   // 1,048,576 (live until gemm_out)
    u16* qkb    = ws + 7340032;   // 4,194,304 (dead after repack_kv -> partLo overlay)
    u16* vb     = ws + 11534336;  // 4,194,304 (dead after repack_kv)
    u16* kpack  = ws + 15728640;  // 4,341,760
    u16* vpack  = ws + 20070400;  // 4,341,760 (ends 24,412,160 u16 = 48.8 MB)
    u16* attnb  = ws;             // overlays xb
    u16* partLo = ws + 7340032;   // 128 slots x 32768 u16 (overlays qkb)
    u16* partHi = ws + 4194304;   // 60 slots (overlays wqkb+wvb)
    float* mlbuf = (float*)d_out; // d_out dead until gemm_out

    cvt_kernel<<<7168, 256, 0, stream>>>(x, Wqk, Wv, Wo, ws);
    gemm_qkv<<<512, 256, 0, stream>>>(xb, wqkb, wvb, bqk, bv, qkb, vb);
    repack_kv<<<530, 256, 0, stream>>>(qkb, vb, kpack, vpack);
    attn_kernel<<<424, 256, 0, stream>>>(kpack, vpack, attnb, partLo, partHi, mlbuf);
    combine_kernel<<<80, 256, 0, stream>>>(partLo, partHi, mlbuf, attnb);
    gemm_out<<<512, 256, 0, stream>>>(attnb, wob, bo, out);
}